// Round 3
// baseline (121.928 us; speedup 1.0000x reference)
//
#include <hip/hip_runtime.h>
#include <stdint.h>

// Exact k-subset sampler, 4-lanes-per-row layout, zero __syncthreads.
// R12: I-cache theory. R9/R10/R11 all plateau at 62-65us with VALUBusy 78-86%
// regardless of occupancy structure; busy-work floor is ~49-54us. The fully
// inlined kernel is ~6-7K instr (~30-45KB) vs 32KB I-cache/CU: ~30 inlined
// gumbel_draw sites (threefry + 2 OCML logf, ~115 instr each) alone are
// ~13KB. Per-wave issue density ~40% = issue starvation consistent with
// I-cache thrash. Fix: OUTLINE gumbel_draw (noinline, one copy), restore
// li3 partial unroll (R9's tuned shape), plus a free exact micro-win:
// L1 lse s = expf(min-max)+1.0f (expf(0)==1.0f exact, IEEE add commutative
// => bitwise identical; saves 4 exact expf/lane).
// Layout (q = lane&3, r = lane>>2, 16 rows/wave, 64-thr blocks, grid 4096):
//   up-pass: lane (p=q&1, g=q>>1) owns a half-subtree: 8 cols, 4 L1, 2 L2,
//     1 L3 (exact OCML). Sibling L3 via shfl_xor(2); L4 m-split across the
//     g-pair (lane g does m in {1+g,3+g,5+g,7+g}, verbatim per-m arithmetic).
//   down-pass: marginals for own 8 cols (fast __expf/__logf path, thr 2e-2).
//   sampling: lane (s=q&1, h=q>>1) runs sample s, subtree h. Root draw split
//     j = 4h+k (j=4 drawn by both halves; combine keeps first-max / low-j on
//     ties). After the root, the subtree is fully lane-local:
//     li1 1 task, li2 2 tasks (static J=5), li3 4 tasks (static J=3),
//     li4 8 leaf pairs (draws only for c==1).
// All skipped draws are infeasible (-1e10 can't win) or argmax-of-one =>
// bitwise-identical samples (PRNG + pruning verified rounds 1-11). All lse
// expression/summation orders copied verbatim from the R9/R11 kernels.
// Single-term conv outputs (conv<3,5> m=4, conv<5,9> m=8) stored as direct
// sums: log(exp(0))=0 exactly (same trick as th2, validated since R3).
// LDS stride 17 (R11): divergent-entry access conflict-free.

__host__ __device__ __forceinline__ void tf2x32(uint32_t k0, uint32_t k1,
                                                uint32_t x0, uint32_t x1,
                                                uint32_t& y0, uint32_t& y1) {
  const uint32_t ks[3] = {k0, k1, k0 ^ k1 ^ 0x1BD11BDAu};
  x0 += ks[0]; x1 += ks[1];
  const int R0[4] = {13, 15, 26, 6};
  const int R1[4] = {17, 29, 16, 24};
#pragma unroll
  for (int i = 0; i < 5; ++i) {
    const int* R = (i & 1) ? R1 : R0;
#pragma unroll
    for (int rr = 0; rr < 4; ++rr) {
      x0 += x1;
      x1 = (x1 << R[rr]) | (x1 >> (32 - R[rr]));
      x1 ^= x0;
    }
    x0 += ks[(i + 1) % 3];
    x1 += ks[(i + 2) % 3] + (uint32_t)(i + 1);
  }
  y0 = x0; y1 = x1;
}

struct TFKeys { uint32_t v[10]; };

// Exact gumbel (OCML logf) — must stay bit-identical to JAX reference.
// R12: noinline — single code copy (~100 instr) instead of ~30 inlined
// sites; shrinks kernel below the 32KB I-cache working set.
__device__ __attribute__((noinline)) float gumbel_draw(uint32_t sk0,
                                                       uint32_t sk1,
                                                       uint32_t f) {
  uint32_t y0, y1;
  tf2x32(sk0, sk1, 0u, f, y0, y1);
  uint32_t bits = y0 ^ y1;
  uint32_t fb = (bits >> 9) | 0x3f800000u;
  float u = __uint_as_float(fb) - 1.0f;
  const float tiny = 1.17549435e-38f;
  float rr = fmaxf(tiny, u + tiny);
  return -logf(-logf(rr));
}

template<bool FAST> __device__ __forceinline__ float expT(float x) {
  return FAST ? __expf(x) : expf(x);
}
template<bool FAST> __device__ __forceinline__ float logT(float x) {
  return FAST ? __logf(x) : logf(x);
}

// o[m] = logsumexp_j aL[j] + aR[m-j] over in-support j, ascending-j sum.
// LS: last output is a single-term lse -> exact direct sum.
template<int SIN, int SOUT, bool FAST, bool LS>
__device__ __forceinline__ void conv_level(const float (&aL)[SIN],
                                           const float (&aR)[SIN],
                                           float (&o)[SOUT]) {
#pragma unroll
  for (int m = 1; m < SOUT; ++m) {
    if (LS && m == SOUT - 1) { o[m] = aL[SIN - 1] + aR[SIN - 1]; continue; }
    const int jlo = (m - (SIN - 1) > 0) ? (m - (SIN - 1)) : 0;
    const int jhi = (m < SIN - 1) ? m : (SIN - 1);
    float t[SIN];
#pragma unroll
    for (int j = 0; j < SIN; ++j)
      if (j >= jlo && j <= jhi) t[j] = aL[j] + aR[m - j];
    float amax = t[jlo];
#pragma unroll
    for (int j = 0; j < SIN; ++j)
      if (j > jlo && j <= jhi) amax = fmaxf(amax, t[j]);
    float s = 0.0f;
#pragma unroll
    for (int j = 0; j < SIN; ++j)
      if (j >= jlo && j <= jhi) s += expT<FAST>(t[j] - amax);
    o[m] = logT<FAST>(s) + amax;
  }
}

// eo[m] = logsumexp_{j=max(0,m-SSIB+1)..m} ein[j] + sib[m-j]
template<int SSIB, int MLO, int MHI, bool FAST>
__device__ __forceinline__ void ext_level(const float (&ein)[8],
                                          const float* sib, float (&eo)[8]) {
#pragma unroll
  for (int m = MLO; m <= MHI; ++m) {
    const int jlo = (m - (SSIB - 1) > 0) ? (m - (SSIB - 1)) : 0;
    float t[8];
#pragma unroll
    for (int j = 0; j < 8; ++j)
      if (j >= jlo && j <= m) t[j] = ein[j] + sib[m - j];
    float amax = t[jlo];
#pragma unroll
    for (int j = 0; j < 8; ++j)
      if (j > jlo && j <= m) amax = fmaxf(amax, t[j]);
    float s = 0.0f;
#pragma unroll
    for (int j = 0; j < 8; ++j)
      if (j >= jlo && j <= m) s += expT<FAST>(t[j] - amax);
    eo[m] = logT<FAST>(s) + amax;
  }
}

// LDS entry map, stride 17 over entries (16 rows + 1 pad float).
// bank(E, r) = (17E + r) & 31. A row's 4 lanes typically touch entries
// {E, E+4, E+8, E+12} -> banks offset by {0,4,8,12}: conflict-free.
// Same-address (uniform E, same r) stays a broadcast.
//  theta col c        : 0..31
//  L1 m=1, node n1    : 32 + n1   (n1 0..15)
//  L1 m=2, node n1    : 48 + n1
//  L2 node n2, m=1..4 : 64 + n2*4 + (m-1)   (n2 0..7)
//  L3 node n3, m=1..8 : 96 + n3*8 + (m-1)   (n3 0..3)
#define ENT 128

__global__ __launch_bounds__(64, 4) void simple_sampler_kernel(
    const float* __restrict__ scores, float* __restrict__ out,
    int nnodes, TFKeys keys) {
  const int lane = threadIdx.x;
  const int q = lane & 3;        // lane-within-row
  const int r = lane >> 2;       // row-local 0..15
  const int p = q & 1;           // up/down pass: subtree id
  const int g = q >> 1;          // up/down pass: half-of-subtree id
  const int row = blockIdx.x * 16 + r;
  const int node = row >> 3, e = row & 7;
  const int B = nnodes * 8;

  __shared__ float tab[ENT * 17];
#define L(E) tab[(E) * 17 + r]

  // ---- load own 8 theta cols (16p+8g .. +7), stash to LDS ----
  float th[8];
  const float* sc = scores + node * 256 + e + (16 * p + 8 * g) * 8;
#pragma unroll
  for (int c = 0; c < 8; ++c) th[c] = sc[c * 8];
#pragma unroll
  for (int c = 0; c < 8; ++c) L(16 * p + 8 * g + c) = th[c];

  // ---- up pass, half-subtree (p,g) only (exact OCML) ----
  float l1r[4], th2r[4];
#pragma unroll
  for (int n1l = 0; n1l < 4; ++n1l) {
    float tL = th[2 * n1l], tR = th[2 * n1l + 1];
    float amax = fmaxf(tR, tL);              // t0 = thR (j=0), t1 = thL
    // expf(max-amax)==expf(0)==1.0f exactly; IEEE add commutative =>
    // bitwise identical to expf(tR-amax)+expf(tL-amax). Saves one exact expf.
    float s = expf(fminf(tR, tL) - amax) + 1.0f;
    l1r[n1l] = logf(s) + amax;
    th2r[n1l] = tL + tR;                      // exact: logf(1.0f)==0.0f
    int n1 = 8 * p + 4 * g + n1l;
    L(32 + n1) = l1r[n1l];
    L(48 + n1) = th2r[n1l];
  }
  float l2r[2][5];
#pragma unroll
  for (int n2l = 0; n2l < 2; ++n2l) {
    float aL[3] = {0.0f, l1r[2 * n2l], th2r[2 * n2l]};
    float aR[3] = {0.0f, l1r[2 * n2l + 1], th2r[2 * n2l + 1]};
    float o5[5];
    conv_level<3, 5, false, true>(aL, aR, o5);
    l2r[n2l][0] = 0.0f;
    int n2 = 4 * p + 2 * g + n2l;
#pragma unroll
    for (int m = 1; m < 5; ++m) { l2r[n2l][m] = o5[m]; L(64 + n2 * 4 + m - 1) = o5[m]; }
  }
  float l3r[9];
  {
    float o9[9];
    conv_level<5, 9, false, true>(l2r[0], l2r[1], o9);
    l3r[0] = 0.0f;
    int n3 = 2 * p + g;
#pragma unroll
    for (int m = 1; m < 9; ++m) { l3r[m] = o9[m]; L(96 + n3 * 8 + m - 1) = o9[m]; }
  }

  // Pin ordering: all up-pass LDS writes precede all cross-lane LDS reads.
  __builtin_amdgcn_wave_barrier();

  // ---- sibling L3 (node 2p + (g^1)) via shfl, no LDS round-trip ----
  float l3s[9];
  l3s[0] = 0.0f;
#pragma unroll
  for (int m = 1; m < 9; ++m) l3s[m] = __shfl_xor(l3r[m], 2);

  // ---- L4 (own subtree p): m-split across the g-pair (no duplication).
  //      Lane g computes m in {1+g, 3+g, 5+g, 7+g}; per-m arithmetic is
  //      verbatim conv_level<9,9> (ascending-j amax/sum, exact OCML).
  //      Masked extra term adds exactly 0.0f; indices all compile-time. ----
  float A0[9], A1[9];
  {
    float aLp[9], aRp[9];
#pragma unroll
    for (int m = 0; m < 9; ++m) {
      aLp[m] = g ? l3s[m] : l3r[m];   // aL = L3[2p]   (even child)
      aRp[m] = g ? l3r[m] : l3s[m];   // aR = L3[2p+1] (odd child)
    }
    float own[4];
#pragma unroll
    for (int mi = 0; mi < 4; ++mi) {
      // m = 2*mi + 1 + g; terms j = 0..m; aR index m-j = (2mi+1-j) + g
      float t[8];
#pragma unroll
      for (int j = 0; j <= 2 * mi + 1; ++j) {
        float aRv = g ? aRp[2 * mi + 2 - j] : aRp[2 * mi + 1 - j];
        t[j] = aLp[j] + aRv;
      }
      float tlast = aLp[2 * mi + 2] + aRp[0];   // j = 2mi+2, valid iff g==1
      float amax = t[0];
#pragma unroll
      for (int j = 1; j <= 2 * mi + 1; ++j) amax = fmaxf(amax, t[j]);
      amax = g ? fmaxf(amax, tlast) : amax;
      float s = 0.0f;
#pragma unroll
      for (int j = 0; j <= 2 * mi + 1; ++j) s += expf(t[j] - amax);
      s += g ? expf(tlast - amax) : 0.0f;       // adds exact 0.0f when g==0
      own[mi] = logf(s) + amax;                 // own slot m = 2mi+1+g
    }
    // gather the other half via shfl_xor(2); assemble full table
    float l4o[9];
#pragma unroll
    for (int mi = 0; mi < 4; ++mi) {
      float oth = __shfl_xor(own[mi], 2);       // slot m = 2mi+2-g
      l4o[2 * mi + 1] = g ? oth : own[mi];      // m odd
      l4o[2 * mi + 2] = g ? own[mi] : oth;      // m even
    }
    A0[0] = 0.0f; A1[0] = 0.0f;
#pragma unroll
    for (int m = 1; m < 9; ++m) {
      float o = l4o[m];
      float oth2 = __shfl_xor(o, 1);
      A0[m] = p ? oth2 : o;
      A1[m] = p ? o : oth2;
    }
  }

  // ---- logZ (marginals only -> fast) ----
  float logZ;
  {
    float tv[9];
#pragma unroll
    for (int j = 0; j < 9; ++j) tv[j] = A0[j] + A1[8 - j];
    float amax = tv[0];
#pragma unroll
    for (int j = 1; j < 9; ++j) amax = fmaxf(amax, tv[j]);
    float s = 0.0f;
#pragma unroll
    for (int j = 0; j < 9; ++j) s += __expf(tv[j] - amax);
    logZ = __logf(s) + amax;
  }

  // ---- down pass, own L3 node only (fast path; marginals only) ----
  {
    float e4v[8];
    e4v[0] = 0.0f;
#pragma unroll
    for (int m = 1; m < 8; ++m) e4v[m] = p ? A0[m] : A1[m];  // sibling of n4=p
    float* mb = out + 2 * B * 32 + node * 256 + e;
    float e3[8];
    ext_level<9, 0, 7, true>(e4v, l3s, e3);                  // sibling L3
#pragma unroll
    for (int c2 = 0; c2 < 2; ++c2) {
      float e2v[8];
      ext_level<5, 4, 7, true>(e3, l2r[c2 ^ 1], e2v);
#pragma unroll
      for (int c1i = 0; c1i < 2; ++c1i) {
        const int n1l = 2 * c2 + c1i;
        float sib1[3] = {0.0f, l1r[n1l ^ 1], th2r[n1l ^ 1]};
        float e1m[8];
        ext_level<3, 6, 7, true>(e2v, sib1, e1m);
        const int colL = 16 * p + 8 * g + 2 * n1l;
        {
          float t6 = e1m[6] + th[2 * n1l + 1];
          float t7 = e1m[7];
          float amax = fmaxf(t6, t7);
          float s = __expf(t6 - amax) + __expf(t7 - amax);
          mb[colL * 8] = __expf((th[2 * n1l] + (__logf(s) + amax)) - logZ);
        }
        {
          float t6 = e1m[6] + th[2 * n1l];
          float t7 = e1m[7];
          float amax = fmaxf(t6, t7);
          float s = __expf(t6 - amax) + __expf(t7 - amax);
          mb[(colL + 1) * 8] = __expf((th[2 * n1l + 1] + (__logf(s) + amax)) - logZ);
        }
      }
    }
  }

  // ---- top-down sampling: lane runs sample s = q&1, subtree h = q>>1 ----
  const int smp = q & 1;
  const int h = q >> 1;
  const uint32_t t9 = (uint32_t)(smp * B + row) * 9u;
  int c;
  {  // root, cooperative across the h-pair: lane h draws j = 4h..4h+4
     // (j=4 drawn by both; identical bits, first-max combine keeps low j)
    float bv = 0.0f; int bj = 0;
#pragma unroll
    for (int k = 0; k < 5; ++k) {
      const int j = 4 * h + k;
      float gd = gumbel_draw(keys.v[0], keys.v[1], t9 + (uint32_t)j);
      float v = (A0[j] + A1[8 - j]) + gd;
      if (k == 0) { bv = v; bj = j; } else if (v > bv) { bv = v; bj = j; }
    }
    float ov = __shfl_xor(bv, 2);
    int   oj = __shfl_xor(bj, 2);
    float vlo = h ? ov : bv;  int jlo = h ? oj : bj;
    float vhi = h ? bv : ov;  int jhi = h ? bj : oj;
    int rootj = (vhi > vlo) ? jhi : jlo;   // ties -> first (low j)
    c = h ? (8 - rootj) : rootj;           // own L4 node's count
  }
  int cA, cB;  // counts for L3 nodes 2h, 2h+1
  {  // li1: single task i = h, feasible j = 0..c (c==0 -> no draw, bj=0)
    int j0 = 0;
    if (c > 0) {
      float b0 = -3.0e38f;
      for (int j = 0; j <= c; ++j) {
        float a = (j == 0) ? 0.0f : L(96 + 16 * h + j - 1);
        float b = (c - j == 0) ? 0.0f : L(96 + 16 * h + 8 + (c - j) - 1);
        float gd = gumbel_draw(keys.v[2], keys.v[3],
                               2u * t9 + (uint32_t)(9 * h + j));
        float v = (a + b) + gd;
        if (v > b0) { b0 = v; j0 = j; }
      }
    }
    cA = j0; cB = c - j0;
  }
  uint32_t pk2 = 0;
  {  // li2: 2 tasks (global i = 2h+i2), J=5 static with validity guard
    int cc0 = cA, cc1 = cB;
#pragma unroll
    for (int i2 = 0; i2 < 2; ++i2) {
      const int i = 2 * h + i2;
      int ci = i2 ? cc1 : cc0;
      float best = -3.0e38f; int bj2 = 0;
#pragma unroll
      for (int j = 0; j < 5; ++j) {
        float gd = gumbel_draw(keys.v[4], keys.v[5],
                               4u * t9 + (uint32_t)(i * 9 + j));
        int idx = ci - j;
        int cl = min(max(idx, 1), 4);
        float b = L(64 + (2 * i + 1) * 4 + cl - 1);
        float bf = (idx == 0) ? 0.0f : b;
        float a = (j == 0) ? 0.0f : L(64 + (2 * i) * 4 + j - 1);
        float v = (a + bf) + gd;
        if (idx >= 0 && idx <= 4 && v > best) { best = v; bj2 = j; }
      }
      pk2 |= ((uint32_t)bj2 << (8 * i2)) | ((uint32_t)(ci - bj2) << (8 * i2 + 4));
    }
  }
  uint32_t pk3 = 0;
  {  // li3: 4 tasks (global i = 4h+i2), J=3 static with validity guard
    const uint32_t sk0 = keys.v[6], sk1 = keys.v[7];
    const uint32_t fb0 = 8u * t9;
#pragma unroll 2
    for (int i2 = 0; i2 < 4; ++i2) {
      const int i = 4 * h + i2;
      int ci = (int)((pk2 >> (4 * i2)) & 15u);
      float aL1 = L(32 + 2 * i), aL2 = L(48 + 2 * i);
      float bR1 = L(32 + 2 * i + 1), bR2 = L(48 + 2 * i + 1);
      uint32_t fb = fb0 + (uint32_t)(i * 9);
      float best = -3.0e38f; int bj3 = 0;
#pragma unroll
      for (int j = 0; j < 3; ++j) {
        float gd = gumbel_draw(sk0, sk1, fb + (uint32_t)j);
        int idx = ci - j;
        float bf = (idx == 1) ? bR1 : ((idx == 2) ? bR2 : 0.0f);
        float af = (j == 0) ? 0.0f : ((j == 1) ? aL1 : aL2);
        float v = (af + bf) + gd;
        if (idx >= 0 && idx <= 2 && v > best) { best = v; bj3 = j; }
      }
      pk3 |= ((uint32_t)bj3 << (8 * i2)) | ((uint32_t)(ci - bj3) << (8 * i2 + 4));
    }
  }
  {  // li4: 8 leaf pairs (global i = 8h+i2); draws ONLY for c==1 pairs
    const uint32_t sk0 = keys.v[8], sk1 = keys.v[9];
    const uint32_t fb0 = 16u * t9;
    float* bs = out + smp * (B * 32) + node * 256 + e;
    uint32_t lst = 0; int m4 = 0;
#pragma unroll
    for (int i2 = 0; i2 < 8; ++i2) {
      int ci = (int)((pk3 >> (4 * i2)) & 15u);
      const int i = 8 * h + i2;
      if (ci == 1) {
        lst |= ((uint32_t)i2) << (4 * m4);
        ++m4;
      } else {
        int bj = ci >> 1;                       // 0->0, 2->1
        bs[16 * i] = (float)bj;
        bs[16 * i + 8] = (float)(ci - bj);
      }
    }
    for (int tt = 0; tt < m4; ++tt) {
      int i2 = (int)((lst >> (4 * tt)) & 15u);
      int i = 8 * h + i2;
      float thL = L(2 * i);
      float thR = L(2 * i + 1);
      uint32_t fb = fb0 + (uint32_t)(i * 9);
      float g0 = gumbel_draw(sk0, sk1, fb);       // j=0: 0 + thR
      float g1 = gumbel_draw(sk0, sk1, fb + 1u);  // j=1: thL + 0
      int bj = ((thL + g1) > (thR + g0)) ? 1 : 0; // first-max: strict >
      bs[16 * i] = (float)bj;
      bs[16 * i + 8] = (float)(1 - bj);
    }
  }
#undef L
}

extern "C" void kernel_launch(void* const* d_in, const int* in_sizes, int n_in,
                              void* d_out, int out_size, void* d_ws, size_t ws_size,
                              hipStream_t stream) {
  const float* scores = (const float*)d_in[0];
  float* out = (float*)d_out;
  const int nnodes = in_sizes[0] / (32 * 8);   // 8192
  const int B = nnodes * 8;                    // 65536 rows

  // key = jax.random.key(42); per level: key, sub = split(key)
  // (partitionable threefry: new = tf(key,(0,0)), sub = tf(key,(0,1)))
  TFKeys K;
  uint32_t k0 = 0u, k1 = 42u;
  for (int t = 0; t < 5; ++t) {
    uint32_t n0, n1, s0, s1;
    tf2x32(k0, k1, 0u, 0u, n0, n1);
    tf2x32(k0, k1, 0u, 1u, s0, s1);
    K.v[2 * t] = s0; K.v[2 * t + 1] = s1;
    k0 = n0; k1 = n1;
  }

  dim3 grid((unsigned)(B / 16)), block(64);
  hipLaunchKernelGGL(simple_sampler_kernel, grid, block, 0, stream,
                     scores, out, nnodes, K);
}

// Round 5
// 119.652 us; speedup vs baseline: 1.0190x; 1.0190x over previous
//
#include <hip/hip_runtime.h>
#include <stdint.h>

// Exact k-subset sampler, 4-lanes-per-row layout, zero __syncthreads.
// R14 == R13 resubmit (R13 bench was an infra failure: container died twice,
// no kernel verdict). Theory unchanged:
// R12's noinline gumbel FAILED (+6.4us: call ABI + lost cross-draw ILP;
// I-cache theory falsified) -> reverted to forceinline.
// R11 vs R9 busy-work delta (+5.2us) localized to WAVE-MAX DRAW COUNTS:
//   li1 per-lane dynamic loop j=0..c has wave-max ~9 (some row has c=8),
//   4 lanes/row = 36 slots vs R9's pair-flat 20. Fix: pair-compaction.
//   - li1 pair-split: flatten both tasks (tot = n0+n1 <= 10), lane h takes
//     t = h, h+2, ... (<=5 trips, straight-line body), per-task merge via
//     shfl_xor(2), first-max tie-break (higher v, tie -> lower j; j monotone
//     in t => identical to sequential first-max). Wave draws 9 -> 5.
//   - li2 pair-compaction: 4 tasks' feasible j in [max(0,c-4), min(4,c)],
//     sum of feasible <= 12 given sum(c)=8 -> <=6 draws/lane vs 10 static.
//     Segment decode = ~20 instr of selects per t vs 130/draw saved.
//   (root j=4 dedup rejected: h-divergent code serializes both paths.)
// Layout (q = lane&3, r = lane>>2, 16 rows/wave, 64-thr blocks, grid 4096):
//   up-pass: lane (p=q&1, g=q>>1) owns a half-subtree: 8 cols, 4 L1, 2 L2,
//     1 L3 (exact OCML). Sibling L3 via shfl_xor(2); L4 m-split across the
//     g-pair (lane g does m in {1+g,3+g,5+g,7+g}, verbatim per-m arithmetic).
//   down-pass: marginals for own 8 cols (fast __expf/__logf path, thr 2e-2).
//   sampling: lane (s=q&1, h=q>>1) runs sample s, subtree h; root draw split
//     j = 4h+k (j=4 drawn by both halves; combine keeps first-max / low-j).
//     li1/li2 pair-compacted (above); li3 4 tasks static J=3 (unroll 2);
//     li4 8 leaf pairs (draws only for c==1).
// All skipped draws are infeasible (-1e10 can't win) or argmax-of-one =>
// bitwise-identical samples (PRNG + pruning verified rounds 1-12). All lse
// expression/summation orders copied verbatim. Single-term conv outputs
// stored as direct sums (log(exp(0))=0 exact). L1 lse uses
// s = expf(min-max)+1.0f (expf(0)==1.0f exact, add commutative => bitwise
// identical). LDS stride 17: divergent-entry access conflict-free.

__host__ __device__ __forceinline__ void tf2x32(uint32_t k0, uint32_t k1,
                                                uint32_t x0, uint32_t x1,
                                                uint32_t& y0, uint32_t& y1) {
  const uint32_t ks[3] = {k0, k1, k0 ^ k1 ^ 0x1BD11BDAu};
  x0 += ks[0]; x1 += ks[1];
  const int R0[4] = {13, 15, 26, 6};
  const int R1[4] = {17, 29, 16, 24};
#pragma unroll
  for (int i = 0; i < 5; ++i) {
    const int* R = (i & 1) ? R1 : R0;
#pragma unroll
    for (int rr = 0; rr < 4; ++rr) {
      x0 += x1;
      x1 = (x1 << R[rr]) | (x1 >> (32 - R[rr]));
      x1 ^= x0;
    }
    x0 += ks[(i + 1) % 3];
    x1 += ks[(i + 2) % 3] + (uint32_t)(i + 1);
  }
  y0 = x0; y1 = x1;
}

struct TFKeys { uint32_t v[10]; };

// Exact gumbel (OCML logf) — must stay bit-identical to JAX reference.
__device__ __forceinline__ float gumbel_draw(uint32_t sk0, uint32_t sk1,
                                             uint32_t f) {
  uint32_t y0, y1;
  tf2x32(sk0, sk1, 0u, f, y0, y1);
  uint32_t bits = y0 ^ y1;
  uint32_t fb = (bits >> 9) | 0x3f800000u;
  float u = __uint_as_float(fb) - 1.0f;
  const float tiny = 1.17549435e-38f;
  float rr = fmaxf(tiny, u + tiny);
  return -logf(-logf(rr));
}

template<bool FAST> __device__ __forceinline__ float expT(float x) {
  return FAST ? __expf(x) : expf(x);
}
template<bool FAST> __device__ __forceinline__ float logT(float x) {
  return FAST ? __logf(x) : logf(x);
}

// o[m] = logsumexp_j aL[j] + aR[m-j] over in-support j, ascending-j sum.
// LS: last output is a single-term lse -> exact direct sum.
template<int SIN, int SOUT, bool FAST, bool LS>
__device__ __forceinline__ void conv_level(const float (&aL)[SIN],
                                           const float (&aR)[SIN],
                                           float (&o)[SOUT]) {
#pragma unroll
  for (int m = 1; m < SOUT; ++m) {
    if (LS && m == SOUT - 1) { o[m] = aL[SIN - 1] + aR[SIN - 1]; continue; }
    const int jlo = (m - (SIN - 1) > 0) ? (m - (SIN - 1)) : 0;
    const int jhi = (m < SIN - 1) ? m : (SIN - 1);
    float t[SIN];
#pragma unroll
    for (int j = 0; j < SIN; ++j)
      if (j >= jlo && j <= jhi) t[j] = aL[j] + aR[m - j];
    float amax = t[jlo];
#pragma unroll
    for (int j = 0; j < SIN; ++j)
      if (j > jlo && j <= jhi) amax = fmaxf(amax, t[j]);
    float s = 0.0f;
#pragma unroll
    for (int j = 0; j < SIN; ++j)
      if (j >= jlo && j <= jhi) s += expT<FAST>(t[j] - amax);
    o[m] = logT<FAST>(s) + amax;
  }
}

// eo[m] = logsumexp_{j=max(0,m-SSIB+1)..m} ein[j] + sib[m-j]
template<int SSIB, int MLO, int MHI, bool FAST>
__device__ __forceinline__ void ext_level(const float (&ein)[8],
                                          const float* sib, float (&eo)[8]) {
#pragma unroll
  for (int m = MLO; m <= MHI; ++m) {
    const int jlo = (m - (SSIB - 1) > 0) ? (m - (SSIB - 1)) : 0;
    float t[8];
#pragma unroll
    for (int j = 0; j < 8; ++j)
      if (j >= jlo && j <= m) t[j] = ein[j] + sib[m - j];
    float amax = t[jlo];
#pragma unroll
    for (int j = 0; j < 8; ++j)
      if (j > jlo && j <= m) amax = fmaxf(amax, t[j]);
    float s = 0.0f;
#pragma unroll
    for (int j = 0; j < 8; ++j)
      if (j >= jlo && j <= m) s += expT<FAST>(t[j] - amax);
    eo[m] = logT<FAST>(s) + amax;
  }
}

// LDS entry map, stride 17 over entries (16 rows + 1 pad float).
// bank(E, r) = (17E + r) & 31. A row's 4 lanes typically touch entries
// {E, E+4, E+8, E+12} -> banks offset by {0,4,8,12}: conflict-free.
// Same-address (uniform E, same r) stays a broadcast.
//  theta col c        : 0..31
//  L1 m=1, node n1    : 32 + n1   (n1 0..15)
//  L1 m=2, node n1    : 48 + n1
//  L2 node n2, m=1..4 : 64 + n2*4 + (m-1)   (n2 0..7)
//  L3 node n3, m=1..8 : 96 + n3*8 + (m-1)   (n3 0..3)
#define ENT 128

__global__ __launch_bounds__(64, 4) void simple_sampler_kernel(
    const float* __restrict__ scores, float* __restrict__ out,
    int nnodes, TFKeys keys) {
  const int lane = threadIdx.x;
  const int q = lane & 3;        // lane-within-row
  const int r = lane >> 2;       // row-local 0..15
  const int p = q & 1;           // up/down pass: subtree id
  const int g = q >> 1;          // up/down pass: half-of-subtree id
  const int row = blockIdx.x * 16 + r;
  const int node = row >> 3, e = row & 7;
  const int B = nnodes * 8;

  __shared__ float tab[ENT * 17];
#define L(E) tab[(E) * 17 + r]

  // ---- load own 8 theta cols (16p+8g .. +7), stash to LDS ----
  float th[8];
  const float* sc = scores + node * 256 + e + (16 * p + 8 * g) * 8;
#pragma unroll
  for (int c = 0; c < 8; ++c) th[c] = sc[c * 8];
#pragma unroll
  for (int c = 0; c < 8; ++c) L(16 * p + 8 * g + c) = th[c];

  // ---- up pass, half-subtree (p,g) only (exact OCML) ----
  float l1r[4], th2r[4];
#pragma unroll
  for (int n1l = 0; n1l < 4; ++n1l) {
    float tL = th[2 * n1l], tR = th[2 * n1l + 1];
    float amax = fmaxf(tR, tL);              // t0 = thR (j=0), t1 = thL
    // expf(max-amax)==expf(0)==1.0f exactly; IEEE add commutative =>
    // bitwise identical to expf(tR-amax)+expf(tL-amax).
    float s = expf(fminf(tR, tL) - amax) + 1.0f;
    l1r[n1l] = logf(s) + amax;
    th2r[n1l] = tL + tR;                      // exact: logf(1.0f)==0.0f
    int n1 = 8 * p + 4 * g + n1l;
    L(32 + n1) = l1r[n1l];
    L(48 + n1) = th2r[n1l];
  }
  float l2r[2][5];
#pragma unroll
  for (int n2l = 0; n2l < 2; ++n2l) {
    float aL[3] = {0.0f, l1r[2 * n2l], th2r[2 * n2l]};
    float aR[3] = {0.0f, l1r[2 * n2l + 1], th2r[2 * n2l + 1]};
    float o5[5];
    conv_level<3, 5, false, true>(aL, aR, o5);
    l2r[n2l][0] = 0.0f;
    int n2 = 4 * p + 2 * g + n2l;
#pragma unroll
    for (int m = 1; m < 5; ++m) { l2r[n2l][m] = o5[m]; L(64 + n2 * 4 + m - 1) = o5[m]; }
  }
  float l3r[9];
  {
    float o9[9];
    conv_level<5, 9, false, true>(l2r[0], l2r[1], o9);
    l3r[0] = 0.0f;
    int n3 = 2 * p + g;
#pragma unroll
    for (int m = 1; m < 9; ++m) { l3r[m] = o9[m]; L(96 + n3 * 8 + m - 1) = o9[m]; }
  }

  // Pin ordering: all up-pass LDS writes precede all cross-lane LDS reads.
  __builtin_amdgcn_wave_barrier();

  // ---- sibling L3 (node 2p + (g^1)) via shfl, no LDS round-trip ----
  float l3s[9];
  l3s[0] = 0.0f;
#pragma unroll
  for (int m = 1; m < 9; ++m) l3s[m] = __shfl_xor(l3r[m], 2);

  // ---- L4 (own subtree p): m-split across the g-pair (no duplication).
  //      Lane g computes m in {1+g, 3+g, 5+g, 7+g}; per-m arithmetic is
  //      verbatim conv_level<9,9> (ascending-j amax/sum, exact OCML).
  //      Masked extra term adds exactly 0.0f; indices all compile-time. ----
  float A0[9], A1[9];
  {
    float aLp[9], aRp[9];
#pragma unroll
    for (int m = 0; m < 9; ++m) {
      aLp[m] = g ? l3s[m] : l3r[m];   // aL = L3[2p]   (even child)
      aRp[m] = g ? l3r[m] : l3s[m];   // aR = L3[2p+1] (odd child)
    }
    float own[4];
#pragma unroll
    for (int mi = 0; mi < 4; ++mi) {
      // m = 2*mi + 1 + g; terms j = 0..m; aR index m-j = (2mi+1-j) + g
      float t[8];
#pragma unroll
      for (int j = 0; j <= 2 * mi + 1; ++j) {
        float aRv = g ? aRp[2 * mi + 2 - j] : aRp[2 * mi + 1 - j];
        t[j] = aLp[j] + aRv;
      }
      float tlast = aLp[2 * mi + 2] + aRp[0];   // j = 2mi+2, valid iff g==1
      float amax = t[0];
#pragma unroll
      for (int j = 1; j <= 2 * mi + 1; ++j) amax = fmaxf(amax, t[j]);
      amax = g ? fmaxf(amax, tlast) : amax;
      float s = 0.0f;
#pragma unroll
      for (int j = 0; j <= 2 * mi + 1; ++j) s += expf(t[j] - amax);
      s += g ? expf(tlast - amax) : 0.0f;       // adds exact 0.0f when g==0
      own[mi] = logf(s) + amax;                 // own slot m = 2mi+1+g
    }
    // gather the other half via shfl_xor(2); assemble full table
    float l4o[9];
#pragma unroll
    for (int mi = 0; mi < 4; ++mi) {
      float oth = __shfl_xor(own[mi], 2);       // slot m = 2mi+2-g
      l4o[2 * mi + 1] = g ? oth : own[mi];      // m odd
      l4o[2 * mi + 2] = g ? own[mi] : oth;      // m even
    }
    A0[0] = 0.0f; A1[0] = 0.0f;
#pragma unroll
    for (int m = 1; m < 9; ++m) {
      float o = l4o[m];
      float oth2 = __shfl_xor(o, 1);
      A0[m] = p ? oth2 : o;
      A1[m] = p ? o : oth2;
    }
  }

  // ---- logZ (marginals only -> fast) ----
  float logZ;
  {
    float tv[9];
#pragma unroll
    for (int j = 0; j < 9; ++j) tv[j] = A0[j] + A1[8 - j];
    float amax = tv[0];
#pragma unroll
    for (int j = 1; j < 9; ++j) amax = fmaxf(amax, tv[j]);
    float s = 0.0f;
#pragma unroll
    for (int j = 0; j < 9; ++j) s += __expf(tv[j] - amax);
    logZ = __logf(s) + amax;
  }

  // ---- down pass, own L3 node only (fast path; marginals only) ----
  {
    float e4v[8];
    e4v[0] = 0.0f;
#pragma unroll
    for (int m = 1; m < 8; ++m) e4v[m] = p ? A0[m] : A1[m];  // sibling of n4=p
    float* mb = out + 2 * B * 32 + node * 256 + e;
    float e3[8];
    ext_level<9, 0, 7, true>(e4v, l3s, e3);                  // sibling L3
#pragma unroll
    for (int c2 = 0; c2 < 2; ++c2) {
      float e2v[8];
      ext_level<5, 4, 7, true>(e3, l2r[c2 ^ 1], e2v);
#pragma unroll
      for (int c1i = 0; c1i < 2; ++c1i) {
        const int n1l = 2 * c2 + c1i;
        float sib1[3] = {0.0f, l1r[n1l ^ 1], th2r[n1l ^ 1]};
        float e1m[8];
        ext_level<3, 6, 7, true>(e2v, sib1, e1m);
        const int colL = 16 * p + 8 * g + 2 * n1l;
        {
          float t6 = e1m[6] + th[2 * n1l + 1];
          float t7 = e1m[7];
          float amax = fmaxf(t6, t7);
          float s = __expf(t6 - amax) + __expf(t7 - amax);
          mb[colL * 8] = __expf((th[2 * n1l] + (__logf(s) + amax)) - logZ);
        }
        {
          float t6 = e1m[6] + th[2 * n1l];
          float t7 = e1m[7];
          float amax = fmaxf(t6, t7);
          float s = __expf(t6 - amax) + __expf(t7 - amax);
          mb[(colL + 1) * 8] = __expf((th[2 * n1l + 1] + (__logf(s) + amax)) - logZ);
        }
      }
    }
  }

  // ---- top-down sampling: lane runs sample s = q&1, subtree h = q>>1 ----
  const int smp = q & 1;
  const int h = q >> 1;
  const uint32_t t9 = (uint32_t)(smp * B + row) * 9u;
  int rootj;
  {  // root, cooperative across the h-pair: lane h draws j = 4h..4h+4
     // (j=4 drawn by both; identical bits, first-max combine keeps low j)
    float bv = 0.0f; int bj = 0;
#pragma unroll
    for (int k = 0; k < 5; ++k) {
      const int j = 4 * h + k;
      float gd = gumbel_draw(keys.v[0], keys.v[1], t9 + (uint32_t)j);
      float v = (A0[j] + A1[8 - j]) + gd;
      if (k == 0) { bv = v; bj = j; } else if (v > bv) { bv = v; bj = j; }
    }
    float ov = __shfl_xor(bv, 2);
    int   oj = __shfl_xor(bj, 2);
    float vlo = h ? ov : bv;  int jlo = h ? oj : bj;
    float vhi = h ? bv : ov;  int jhi = h ? bj : oj;
    rootj = (vhi > vlo) ? jhi : jlo;   // ties -> first (low j)
  }
  int cA, cB;  // counts for L3 nodes 2h, 2h+1 (own subtree h's split)
  {  // li1 pair-compacted: tasks ii=0 (count rootj), ii=1 (count 8-rootj);
     // flat t over both tasks (tot <= 10); lane h takes t = h, h+2, ...
     // (<=5 trips); per-task first-max merged across the pair via shfl.
    const int c0r = rootj, c1r = 8 - rootj;
    const int n0 = c0r ? c0r + 1 : 0;
    const int n1c = c1r ? c1r + 1 : 0;
    const int tot = n0 + n1c;
    float b0 = -3.0e38f, b1 = -3.0e38f;
    int j0 = 0, j1 = 0;
    for (int t = h; t < tot; t += 2) {
      const bool is1 = (t >= n0);
      const int j = is1 ? (t - n0) : t;
      const int ii = is1 ? 1 : 0;
      const int cc = is1 ? c1r : c0r;
      const int idx = cc - j;
      float a = (j == 0) ? 0.0f : L(96 + 16 * ii + j - 1);
      float b = (idx == 0) ? 0.0f : L(96 + 16 * ii + 8 + idx - 1);
      float gd = gumbel_draw(keys.v[2], keys.v[3],
                             2u * t9 + (uint32_t)(9 * ii + j));
      float v = (a + b) + gd;
      if (is1) { if (v > b1) { b1 = v; j1 = j; } }
      else     { if (v > b0) { b0 = v; j0 = j; } }
    }
    {  // merge (first-max == higher v, exact tie -> lower j; j monotone in t)
      float ob0 = __shfl_xor(b0, 2); int oj0 = __shfl_xor(j0, 2);
      float ob1 = __shfl_xor(b1, 2); int oj1 = __shfl_xor(j1, 2);
      if (!(b0 > ob0 || (b0 == ob0 && j0 <= oj0))) j0 = oj0;
      if (!(b1 > ob1 || (b1 == ob1 && j1 <= oj1))) j1 = oj1;
    }
    const int jh = h ? j1 : j0;
    const int ch = h ? c1r : c0r;
    cA = jh; cB = ch - jh;
  }
  uint32_t pk2 = 0;
  {  // li2 pair-compacted: 4 tasks (L3 nodes 0..3), feasible j in
     // [max(0,c-4), min(4,c)]; sum of feasible <= 12 (sum c = 8) ->
     // <=6 draws/lane. Segment decode by selects; per-task shfl merge.
    const int oA = __shfl_xor(cA, 2), oB = __shfl_xor(cB, 2);
    const int tc0 = h ? oA : cA, tc1 = h ? oB : cB;
    const int tc2 = h ? cA : oA, tc3 = h ? cB : oB;
    const int jl0 = max(0, tc0 - 4), nf0 = min(4, tc0) - jl0 + 1;
    const int jl1 = max(0, tc1 - 4), nf1 = min(4, tc1) - jl1 + 1;
    const int jl2 = max(0, tc2 - 4), nf2 = min(4, tc2) - jl2 + 1;
    const int jl3 = max(0, tc3 - 4), nf3 = min(4, tc3) - jl3 + 1;
    const int s1 = nf0, s2 = s1 + nf1, s3 = s2 + nf2, tot = s3 + nf3;
    float bv0 = -3.0e38f, bv1 = -3.0e38f, bv2 = -3.0e38f, bv3 = -3.0e38f;
    int bj0 = 0, bj1 = 0, bj2 = 0, bj3 = 0;
    for (int t = h; t < tot; t += 2) {
      const int i = (t >= s1) + (t >= s2) + (t >= s3);
      const int base = (i == 0) ? 0 : ((i == 1) ? s1 : ((i == 2) ? s2 : s3));
      const int jlo = (i == 0) ? jl0 : ((i == 1) ? jl1 : ((i == 2) ? jl2 : jl3));
      const int ci  = (i == 0) ? tc0 : ((i == 1) ? tc1 : ((i == 2) ? tc2 : tc3));
      const int j = jlo + (t - base);
      const int idx = ci - j;            // in [0,4] by construction
      float a = (j == 0) ? 0.0f : L(64 + (2 * i) * 4 + j - 1);
      float b = (idx == 0) ? 0.0f : L(64 + (2 * i + 1) * 4 + idx - 1);
      float gd = gumbel_draw(keys.v[4], keys.v[5],
                             4u * t9 + (uint32_t)(i * 9 + j));
      float v = (a + b) + gd;
      if (i == 0)      { if (v > bv0) { bv0 = v; bj0 = j; } }
      else if (i == 1) { if (v > bv1) { bv1 = v; bj1 = j; } }
      else if (i == 2) { if (v > bv2) { bv2 = v; bj2 = j; } }
      else             { if (v > bv3) { bv3 = v; bj3 = j; } }
    }
    {  // per-task merge across the pair (tie -> lower j; j monotone in t)
      float ob; int oj;
      ob = __shfl_xor(bv0, 2); oj = __shfl_xor(bj0, 2);
      if (!(bv0 > ob || (bv0 == ob && bj0 <= oj))) bj0 = oj;
      ob = __shfl_xor(bv1, 2); oj = __shfl_xor(bj1, 2);
      if (!(bv1 > ob || (bv1 == ob && bj1 <= oj))) bj1 = oj;
      ob = __shfl_xor(bv2, 2); oj = __shfl_xor(bj2, 2);
      if (!(bv2 > ob || (bv2 == ob && bj2 <= oj))) bj2 = oj;
      ob = __shfl_xor(bv3, 2); oj = __shfl_xor(bj3, 2);
      if (!(bv3 > ob || (bv3 == ob && bj3 <= oj))) bj3 = oj;
    }
    // own tasks are 2h, 2h+1 -> nibble-packed counts of L2 nodes 4h..4h+3
    const int jA = h ? bj2 : bj0;  const int cTA = h ? tc2 : tc0;
    const int jB = h ? bj3 : bj1;  const int cTB = h ? tc3 : tc1;
    pk2 = (uint32_t)jA | ((uint32_t)(cTA - jA) << 4)
        | ((uint32_t)jB << 8) | ((uint32_t)(cTB - jB) << 12);
  }
  uint32_t pk3 = 0;
  {  // li3: 4 tasks (global i = 4h+i2), J=3 static with validity guard
    const uint32_t sk0 = keys.v[6], sk1 = keys.v[7];
    const uint32_t fb0 = 8u * t9;
#pragma unroll 2
    for (int i2 = 0; i2 < 4; ++i2) {
      const int i = 4 * h + i2;
      int ci = (int)((pk2 >> (4 * i2)) & 15u);
      float aL1 = L(32 + 2 * i), aL2 = L(48 + 2 * i);
      float bR1 = L(32 + 2 * i + 1), bR2 = L(48 + 2 * i + 1);
      uint32_t fb = fb0 + (uint32_t)(i * 9);
      float best = -3.0e38f; int bj3 = 0;
#pragma unroll
      for (int j = 0; j < 3; ++j) {
        float gd = gumbel_draw(sk0, sk1, fb + (uint32_t)j);
        int idx = ci - j;
        float bf = (idx == 1) ? bR1 : ((idx == 2) ? bR2 : 0.0f);
        float af = (j == 0) ? 0.0f : ((j == 1) ? aL1 : aL2);
        float v = (af + bf) + gd;
        if (idx >= 0 && idx <= 2 && v > best) { best = v; bj3 = j; }
      }
      pk3 |= ((uint32_t)bj3 << (8 * i2)) | ((uint32_t)(ci - bj3) << (8 * i2 + 4));
    }
  }
  {  // li4: 8 leaf pairs (global i = 8h+i2); draws ONLY for c==1 pairs
    const uint32_t sk0 = keys.v[8], sk1 = keys.v[9];
    const uint32_t fb0 = 16u * t9;
    float* bs = out + smp * (B * 32) + node * 256 + e;
    uint32_t lst = 0; int m4 = 0;
#pragma unroll
    for (int i2 = 0; i2 < 8; ++i2) {
      int ci = (int)((pk3 >> (4 * i2)) & 15u);
      const int i = 8 * h + i2;
      if (ci == 1) {
        lst |= ((uint32_t)i2) << (4 * m4);
        ++m4;
      } else {
        int bj = ci >> 1;                       // 0->0, 2->1
        bs[16 * i] = (float)bj;
        bs[16 * i + 8] = (float)(ci - bj);
      }
    }
    for (int tt = 0; tt < m4; ++tt) {
      int i2 = (int)((lst >> (4 * tt)) & 15u);
      int i = 8 * h + i2;
      float thL = L(2 * i);
      float thR = L(2 * i + 1);
      uint32_t fb = fb0 + (uint32_t)(i * 9);
      float g0 = gumbel_draw(sk0, sk1, fb);       // j=0: 0 + thR
      float g1 = gumbel_draw(sk0, sk1, fb + 1u);  // j=1: thL + 0
      int bj = ((thL + g1) > (thR + g0)) ? 1 : 0; // first-max: strict >
      bs[16 * i] = (float)bj;
      bs[16 * i + 8] = (float)(1 - bj);
    }
  }
#undef L
}

extern "C" void kernel_launch(void* const* d_in, const int* in_sizes, int n_in,
                              void* d_out, int out_size, void* d_ws, size_t ws_size,
                              hipStream_t stream) {
  const float* scores = (const float*)d_in[0];
  float* out = (float*)d_out;
  const int nnodes = in_sizes[0] / (32 * 8);   // 8192
  const int B = nnodes * 8;                    // 65536 rows

  // key = jax.random.key(42); per level: key, sub = split(key)
  // (partitionable threefry: new = tf(key,(0,0)), sub = tf(key,(0,1)))
  TFKeys K;
  uint32_t k0 = 0u, k1 = 42u;
  for (int t = 0; t < 5; ++t) {
    uint32_t n0, n1, s0, s1;
    tf2x32(k0, k1, 0u, 0u, n0, n1);
    tf2x32(k0, k1, 0u, 1u, s0, s1);
    K.v[2 * t] = s0; K.v[2 * t + 1] = s1;
    k0 = n0; k1 = n1;
  }

  dim3 grid((unsigned)(B / 16)), block(64);
  hipLaunchKernelGGL(simple_sampler_kernel, grid, block, 0, stream,
                     scores, out, nnodes, K);
}

// Round 6
// 113.872 us; speedup vs baseline: 1.0707x; 1.0508x over previous
//
#include <hip/hip_runtime.h>
#include <stdint.h>

// Exact k-subset sampler, pair-per-row layout, zero __syncthreads.
// R15 = R9 revert + bitwise-free 2-term lse trims.
// History: R10 (4-lane occupancy) +3.5us (L4 dup + bank conflicts);
// R11 (m-split + stride17) still +2.6us vs R9 (split overheads);
// R12 (noinline gumbel) +6.4us (call ABI + lost ILP);
// R13/14 (pair-compacted li1/li2) +3.4us vs R11 (decode/divergence +
// lost static-unroll ILP beat the saved draws). Lesson: static unrolled
// draws win; R9's 2-lane layout has the least overhead (busy 48.7us,
// VALUBusy 78.6% -> issue-bound plateau).
// R15 trims (all bitwise-identical by IEEE add commutativity +
// expf(0)==1.0f exact, logf(1)==0 exact):
//   - every 2-term lse: s = expT(fmin-fmax) + 1.0f  (saves one exact expf
//     at L1 x8, conv35 m={1,3} x4, conv59 m={1,7} x2, conv99 m=1, and one
//     fast __expf at each of 16 leaf-marginal lse's)
//   - ext_level 1-term m==jlo: o = t[jlo] directly (exp/log of 0/1 exact).
// Layout (wave = 32 rows x 2 lanes, r = lane>>1, p = lane&1):
//   - up-pass split by p (exact OCML); L4 exchanged via shfl_xor (no LDS).
//   - down-pass split by p (fast __expf/__logf; marginals only, thr 2e-2).
//   - sampling: lane p runs sample p. li1 flat-compacted (<=10 draws),
//     li2/li3 static unrolled, li4 draws only for c==1 pairs.
//     All skipped draws are infeasible (-1e10 can't win) or argmax-of-one =>
//     bitwise-identical samples (PRNG + pruning verified rounds 1-9).
// Single-term conv outputs (conv<3,5> m=4, conv<5,9> m=8) stored as direct
// sums: log(exp(0))=0 exactly (same trick as th2, validated since R3).

__host__ __device__ __forceinline__ void tf2x32(uint32_t k0, uint32_t k1,
                                                uint32_t x0, uint32_t x1,
                                                uint32_t& y0, uint32_t& y1) {
  const uint32_t ks[3] = {k0, k1, k0 ^ k1 ^ 0x1BD11BDAu};
  x0 += ks[0]; x1 += ks[1];
  const int R0[4] = {13, 15, 26, 6};
  const int R1[4] = {17, 29, 16, 24};
#pragma unroll
  for (int i = 0; i < 5; ++i) {
    const int* R = (i & 1) ? R1 : R0;
#pragma unroll
    for (int rr = 0; rr < 4; ++rr) {
      x0 += x1;
      x1 = (x1 << R[rr]) | (x1 >> (32 - R[rr]));
      x1 ^= x0;
    }
    x0 += ks[(i + 1) % 3];
    x1 += ks[(i + 2) % 3] + (uint32_t)(i + 1);
  }
  y0 = x0; y1 = x1;
}

struct TFKeys { uint32_t v[10]; };

// Exact gumbel (OCML logf) — must stay bit-identical to JAX reference.
__device__ __forceinline__ float gumbel_draw(uint32_t sk0, uint32_t sk1,
                                             uint32_t f) {
  uint32_t y0, y1;
  tf2x32(sk0, sk1, 0u, f, y0, y1);
  uint32_t bits = y0 ^ y1;
  uint32_t fb = (bits >> 9) | 0x3f800000u;
  float u = __uint_as_float(fb) - 1.0f;
  const float tiny = 1.17549435e-38f;
  float rr = fmaxf(tiny, u + tiny);
  return -logf(-logf(rr));
}

template<bool FAST> __device__ __forceinline__ float expT(float x) {
  return FAST ? __expf(x) : expf(x);
}
template<bool FAST> __device__ __forceinline__ float logT(float x) {
  return FAST ? __logf(x) : logf(x);
}

// o[m] = logsumexp_j aL[j] + aR[m-j] over in-support j, ascending-j sum.
// LS: last output is a single-term lse -> exact direct sum.
// 2-term m: s = expT(fmin-fmax)+1.0f — bitwise identical (expf(0)==1.0f
// exact; single IEEE add is commutative). All branches compile-time.
template<int SIN, int SOUT, bool FAST, bool LS>
__device__ __forceinline__ void conv_level(const float (&aL)[SIN],
                                           const float (&aR)[SIN],
                                           float (&o)[SOUT]) {
#pragma unroll
  for (int m = 1; m < SOUT; ++m) {
    if (LS && m == SOUT - 1) { o[m] = aL[SIN - 1] + aR[SIN - 1]; continue; }
    const int jlo = (m - (SIN - 1) > 0) ? (m - (SIN - 1)) : 0;
    const int jhi = (m < SIN - 1) ? m : (SIN - 1);
    if (jhi - jlo == 1) {
      float ta = aL[jlo] + aR[m - jlo];
      float tb = aL[jhi] + aR[m - jhi];
      float amax = fmaxf(ta, tb);
      o[m] = logT<FAST>(expT<FAST>(fminf(ta, tb) - amax) + 1.0f) + amax;
      continue;
    }
    float t[SIN];
#pragma unroll
    for (int j = 0; j < SIN; ++j)
      if (j >= jlo && j <= jhi) t[j] = aL[j] + aR[m - j];
    float amax = t[jlo];
#pragma unroll
    for (int j = 0; j < SIN; ++j)
      if (j > jlo && j <= jhi) amax = fmaxf(amax, t[j]);
    float s = 0.0f;
#pragma unroll
    for (int j = 0; j < SIN; ++j)
      if (j >= jlo && j <= jhi) s += expT<FAST>(t[j] - amax);
    o[m] = logT<FAST>(s) + amax;
  }
}

// eo[m] = logsumexp_{j=max(0,m-SSIB+1)..m} ein[j] + sib[m-j]
// 1-term m (m==jlo): o = t[jlo] (exp(0)==1, log(1)==0 exact).
// 2-term m: min/max trick as in conv_level.
template<int SSIB, int MLO, int MHI, bool FAST>
__device__ __forceinline__ void ext_level(const float (&ein)[8],
                                          const float* sib, float (&eo)[8]) {
#pragma unroll
  for (int m = MLO; m <= MHI; ++m) {
    const int jlo = (m - (SSIB - 1) > 0) ? (m - (SSIB - 1)) : 0;
    if (m == jlo) { eo[m] = ein[jlo] + sib[m - jlo]; continue; }
    if (m - jlo == 1) {
      float ta = ein[jlo] + sib[m - jlo];
      float tb = ein[m] + sib[0];
      float amax = fmaxf(ta, tb);
      eo[m] = logT<FAST>(expT<FAST>(fminf(ta, tb) - amax) + 1.0f) + amax;
      continue;
    }
    float t[8];
#pragma unroll
    for (int j = 0; j < 8; ++j)
      if (j >= jlo && j <= m) t[j] = ein[j] + sib[m - j];
    float amax = t[jlo];
#pragma unroll
    for (int j = 0; j < 8; ++j)
      if (j > jlo && j <= m) amax = fmaxf(amax, t[j]);
    float s = 0.0f;
#pragma unroll
    for (int j = 0; j < 8; ++j)
      if (j >= jlo && j <= m) s += expT<FAST>(t[j] - amax);
    eo[m] = logT<FAST>(s) + amax;
  }
}

// LDS entry map (stride 32 over r; bank = r%32 -> uniform-entry access is
// 32 banks x 2-way broadcast; divergent-entry access stays in own bank with
// at most 2-way pair alias = free):
//  theta col c        : 0..31
//  L1 m=1, node n1    : 32 + n1   (n1 0..15)
//  L1 m=2, node n1    : 48 + n1
//  L2 node n2, m=1..4 : 64 + n2*4 + (m-1)   (n2 0..7)
//  L3 node n3, m=1..8 : 96 + n3*8 + (m-1)   (n3 0..3)
#define ENT 128

__global__ __launch_bounds__(64, 2) void simple_sampler_kernel(
    const float* __restrict__ scores, float* __restrict__ out,
    int nnodes, TFKeys keys) {
  const int lane = threadIdx.x;
  const int p = lane & 1;        // sample id / subtree id for this lane
  const int r = lane >> 1;       // row-local 0..31
  const int row = blockIdx.x * 32 + r;
  const int node = row >> 3, e = row & 7;
  const int B = nnodes * 8;

  __shared__ float tab[ENT * 32];
#define L(E) tab[(E) * 32 + r]

  // ---- load own-half theta (16 cols), stash to LDS ----
  float th[16];
  const float* sc = scores + node * 256 + e + p * 128;
#pragma unroll
  for (int c = 0; c < 16; ++c) th[c] = sc[c * 8];
#pragma unroll
  for (int c = 0; c < 16; ++c) L(16 * p + c) = th[c];

  // ---- up pass, subtree n4 = p only (exact OCML) ----
  float l1r[8], th2r[8];
#pragma unroll
  for (int n1l = 0; n1l < 8; ++n1l) {
    float tL = th[2 * n1l], tR = th[2 * n1l + 1];
    float amax = fmaxf(tR, tL);              // t0 = thR (j=0), t1 = thL
    // expf(max-amax)==1.0f exactly; 2-term add commutative => bitwise same.
    float s = expf(fminf(tR, tL) - amax) + 1.0f;
    l1r[n1l] = logf(s) + amax;
    th2r[n1l] = tL + tR;                      // exact: logf(1.0f)==0.0f
    int n1 = 8 * p + n1l;
    L(32 + n1) = l1r[n1l];
    L(48 + n1) = th2r[n1l];
  }
  float l2r[4][5];
#pragma unroll
  for (int n2l = 0; n2l < 4; ++n2l) {
    float aL[3] = {0.0f, l1r[2 * n2l], th2r[2 * n2l]};
    float aR[3] = {0.0f, l1r[2 * n2l + 1], th2r[2 * n2l + 1]};
    float o5[5];
    conv_level<3, 5, false, true>(aL, aR, o5);
    l2r[n2l][0] = 0.0f;
    int n2 = 4 * p + n2l;
#pragma unroll
    for (int m = 1; m < 5; ++m) { l2r[n2l][m] = o5[m]; L(64 + n2 * 4 + m - 1) = o5[m]; }
  }
  float l3r[2][9];
#pragma unroll
  for (int n3l = 0; n3l < 2; ++n3l) {
    float o9[9];
    conv_level<5, 9, false, true>(l2r[2 * n3l], l2r[2 * n3l + 1], o9);
    l3r[n3l][0] = 0.0f;
    int n3 = 2 * p + n3l;
#pragma unroll
    for (int m = 1; m < 9; ++m) { l3r[n3l][m] = o9[m]; L(96 + n3 * 8 + m - 1) = o9[m]; }
  }

  // Pin ordering: all up-pass LDS writes precede all cross-half LDS reads.
  __builtin_amdgcn_wave_barrier();

  // ---- L4 node p in regs; exchange via shfl (no LDS, no barrier needed) ----
  float A0[9], A1[9];
  {
    float l4o[9];
    conv_level<9, 9, false, false>(l3r[0], l3r[1], l4o);
    A0[0] = 0.0f; A1[0] = 0.0f;
#pragma unroll
    for (int m = 1; m < 9; ++m) {
      float own = l4o[m];
      float oth = __shfl_xor(own, 1);
      A0[m] = p ? oth : own;
      A1[m] = p ? own : oth;
    }
  }

  // ---- logZ (marginals only -> fast) ----
  float logZ;
  {
    float tv[9];
#pragma unroll
    for (int j = 0; j < 9; ++j) tv[j] = A0[j] + A1[8 - j];
    float amax = tv[0];
#pragma unroll
    for (int j = 1; j < 9; ++j) amax = fmaxf(amax, tv[j]);
    float s = 0.0f;
#pragma unroll
    for (int j = 0; j < 9; ++j) s += __expf(tv[j] - amax);
    logZ = __logf(s) + amax;
  }

  // ---- down pass, subtrees n3 in {2p, 2p+1} (fast path; marginals only) ----
  {
    float e4v[8];
    e4v[0] = 0.0f;
#pragma unroll
    for (int m = 1; m < 8; ++m) e4v[m] = p ? A0[m] : A1[m];  // sibling of n4=p
    float* mb = out + 2 * B * 32 + node * 256 + e;
#pragma unroll
    for (int n3l = 0; n3l < 2; ++n3l) {
      float e3[8];
      ext_level<9, 0, 7, true>(e4v, l3r[n3l ^ 1], e3);
#pragma unroll
      for (int c2 = 0; c2 < 2; ++c2) {
        const int n2l = 2 * n3l + c2;
        float e2v[8];
        ext_level<5, 4, 7, true>(e3, l2r[n2l ^ 1], e2v);
#pragma unroll
        for (int c1i = 0; c1i < 2; ++c1i) {
          const int n1l = 2 * n2l + c1i;
          float sib1[3] = {0.0f, l1r[n1l ^ 1], th2r[n1l ^ 1]};
          float e1m[8];
          ext_level<3, 6, 7, true>(e2v, sib1, e1m);
          const int colL = 16 * p + 2 * n1l;
          {
            float t6 = e1m[6] + th[2 * n1l + 1];
            float t7 = e1m[7];
            float amax = fmaxf(t6, t7);
            float s = __expf(fminf(t6, t7) - amax) + 1.0f;
            mb[colL * 8] = __expf((th[2 * n1l] + (__logf(s) + amax)) - logZ);
          }
          {
            float t6 = e1m[6] + th[2 * n1l];
            float t7 = e1m[7];
            float amax = fmaxf(t6, t7);
            float s = __expf(fminf(t6, t7) - amax) + 1.0f;
            mb[(colL + 1) * 8] = __expf((th[2 * n1l + 1] + (__logf(s) + amax)) - logZ);
          }
        }
      }
    }
  }

  // ---- top-down sampling, sample s = p (bit-exact path) ----
  const uint32_t t9 = (uint32_t)(p * B + row) * 9u;
  int c0, c1;
  {  // root, c = 8, static (A0/A1 regs)
    float best = 0.0f; int bj = 0;
#pragma unroll
    for (int j = 0; j < 9; ++j) {
      float g = gumbel_draw(keys.v[0], keys.v[1], t9 + (uint32_t)j);
      float v = (A0[j] + A1[8 - j]) + g;
      if (j == 0) { best = v; } else if (v > best) { best = v; bj = j; }
    }
    c0 = bj; c1 = 8 - bj;
  }
  int c1v[4];
  {  // li1: flat loop, feasible j = 0..c (c==0 -> no draw, bj=0)
    const int n0 = c0 ? c0 + 1 : 0;
    const int n1c = c1 ? c1 + 1 : 0;
    const int tot = n0 + n1c;
    float b0 = -3.0e38f, b1 = -3.0e38f;
    int j0 = 0, j1 = 0;
    for (int t = 0; t < tot; ++t) {
      const bool is1 = (t >= n0);
      const int j = is1 ? (t - n0) : t;
      const int c = is1 ? c1 : c0;
      const int i = is1 ? 1 : 0;
      const int idx = c - j;
      float a = (j == 0) ? 0.0f : L(96 + 16 * i + j - 1);
      float b = (idx == 0) ? 0.0f : L(96 + 16 * i + 8 + idx - 1);
      float g = gumbel_draw(keys.v[2], keys.v[3],
                            2u * t9 + (uint32_t)(9 * i + j));
      float v = (a + b) + g;
      if (is1) { if (v > b1) { b1 = v; j1 = j; } }
      else     { if (v > b0) { b0 = v; j0 = j; } }
    }
    c1v[0] = j0; c1v[1] = c0 - j0; c1v[2] = j1; c1v[3] = c1 - j1;
  }
  uint32_t pk2 = 0;
  {  // li2: 4 tasks, J=5 static with validity guard (low overhead per draw)
#pragma unroll
    for (int i = 0; i < 4; ++i) {
      int c = c1v[i];
      float best = -3.0e38f; int bj2 = 0;
#pragma unroll
      for (int j = 0; j < 5; ++j) {
        float g = gumbel_draw(keys.v[4], keys.v[5],
                              4u * t9 + (uint32_t)(i * 9 + j));
        int idx = c - j;
        int cl = min(max(idx, 1), 4);
        float b = L(64 + (2 * i + 1) * 4 + cl - 1);
        float bf = (idx == 0) ? 0.0f : b;
        float a = (j == 0) ? 0.0f : L(64 + (2 * i) * 4 + j - 1);
        float v = (a + bf) + g;
        if (idx >= 0 && idx <= 4 && v > best) { best = v; bj2 = j; }
      }
      pk2 |= ((uint32_t)bj2 << (8 * i)) | ((uint32_t)(c - bj2) << (8 * i + 4));
    }
  }
  uint64_t pk64 = 0;
  {  // li3: 8 tasks, J=3 static with validity guard
    const uint32_t sk0 = keys.v[6], sk1 = keys.v[7];
    const uint32_t fb0 = 8u * t9;
#pragma unroll 2
    for (int i = 0; i < 8; ++i) {
      int c = (int)((pk2 >> (4 * i)) & 15u);
      float aL1 = L(32 + 2 * i), aL2 = L(48 + 2 * i);
      float bR1 = L(32 + 2 * i + 1), bR2 = L(48 + 2 * i + 1);
      uint32_t fb = fb0 + (uint32_t)(i * 9);
      float best = -3.0e38f; int bj3 = 0;
#pragma unroll
      for (int j = 0; j < 3; ++j) {
        float g = gumbel_draw(sk0, sk1, fb + (uint32_t)j);
        int idx = c - j;
        float bf = (idx == 1) ? bR1 : ((idx == 2) ? bR2 : 0.0f);
        float af = (j == 0) ? 0.0f : ((j == 1) ? aL1 : aL2);
        float v = (af + bf) + g;
        if (idx >= 0 && idx <= 2 && v > best) { best = v; bj3 = j; }
      }
      pk64 |= ((uint64_t)(uint32_t)bj3 << (8 * i)) |
              ((uint64_t)(uint32_t)(c - bj3) << (8 * i + 4));
    }
  }
  {  // li4: draws ONLY for c==1 leaf pairs (c=0 -> bj=0, c=2 -> bj=1)
    const uint32_t sk0 = keys.v[8], sk1 = keys.v[9];
    const uint32_t fb0 = 16u * t9;
    float* bs = out + p * (B * 32) + node * 256 + e;
    uint64_t lst = 0; int m4 = 0;
#pragma unroll
    for (int i = 0; i < 16; ++i) {
      int c = (int)((uint32_t)(pk64 >> (4 * i)) & 15u);
      if (c == 1) {
        lst |= ((uint64_t)(uint32_t)i) << (4 * m4);
        ++m4;
      } else {
        int bj = c >> 1;                        // 0->0, 2->1
        bs[16 * i] = (float)bj;
        bs[16 * i + 8] = (float)(c - bj);
      }
    }
    for (int tt = 0; tt < m4; ++tt) {
      int i = (int)((lst >> (4 * tt)) & 15u);
      float thL = L(2 * i);
      float thR = L(2 * i + 1);
      uint32_t fb = fb0 + (uint32_t)(i * 9);
      float g0 = gumbel_draw(sk0, sk1, fb);       // j=0: 0 + thR
      float g1 = gumbel_draw(sk0, sk1, fb + 1u);  // j=1: thL + 0
      int bj = ((thL + g1) > (thR + g0)) ? 1 : 0; // first-max: strict >
      bs[16 * i] = (float)bj;
      bs[16 * i + 8] = (float)(1 - bj);
    }
  }
#undef L
}

extern "C" void kernel_launch(void* const* d_in, const int* in_sizes, int n_in,
                              void* d_out, int out_size, void* d_ws, size_t ws_size,
                              hipStream_t stream) {
  const float* scores = (const float*)d_in[0];
  float* out = (float*)d_out;
  const int nnodes = in_sizes[0] / (32 * 8);   // 8192
  const int B = nnodes * 8;                    // 65536 rows

  // key = jax.random.key(42); per level: key, sub = split(key)
  // (partitionable threefry: new = tf(key,(0,0)), sub = tf(key,(0,1)))
  TFKeys K;
  uint32_t k0 = 0u, k1 = 42u;
  for (int t = 0; t < 5; ++t) {
    uint32_t n0, n1, s0, s1;
    tf2x32(k0, k1, 0u, 0u, n0, n1);
    tf2x32(k0, k1, 0u, 1u, s0, s1);
    K.v[2 * t] = s0; K.v[2 * t + 1] = s1;
    k0 = n0; k1 = n1;
  }

  dim3 grid((unsigned)(B / 32)), block(64);
  hipLaunchKernelGGL(simple_sampler_kernel, grid, block, 0, stream,
                     scores, out, nnodes, K);
}

// Round 7
// 111.282 us; speedup vs baseline: 1.0957x; 1.0233x over previous
//
#include <hip/hip_runtime.h>
#include <stdint.h>

// Exact k-subset sampler, pair-per-row layout, zero __syncthreads.
// R16 = R15 + li1 STATIC UNROLL (the last rolled draw loop).
// R15 post-mortem: 2-term lse trims won as modeled (62.0 -> 61.3us/dispatch,
// busy 48.7 -> 47.2us). Remaining gap = 23% VALU idle at 2 waves/SIMD.
// li1 was the only dynamic-trip draw loop (tot in {9,10}) -> compiler keeps
// it rolled -> each iteration's two OCML logf chains (~60cy serial) expose
// ILP of 1. Wave cost is already wave-max(tot)~10 via exec-masking, so a
// static 10-slot unroll with live=(t<tot) guard adds ZERO wave-level work
// and pipelines 10 independent draws. Dead slots (t=9 when tot=9) read
// in-bounds garbage (L(118)/L(120) < ENT=128) and never update => bitwise
// identical first-max. li4 stays list-compacted (wave-max m4 ~12 < 16).
// History: R10 4-lane +3.5us; R11 m-split +2.6us; R12 noinline +6.4us;
// R13 pair-compaction +3.4us. Lesson: static unrolled draws win; R9 2-lane
// structure is the optimum; only micro-trims (R15) and ILP (this) remain.
// R15 trims (bitwise-identical: IEEE add commutative, expf(0)==1.0f exact,
// logf(1)==0 exact): 2-term lse s = expT(fmin-fmax)+1.0f everywhere;
// ext_level 1-term m==jlo direct. Single-term conv outputs as direct sums.
// Layout (wave = 32 rows x 2 lanes, r = lane>>1, p = lane&1):
//   - up-pass split by p (exact OCML); L4 exchanged via shfl_xor (no LDS).
//   - down-pass split by p (fast __expf/__logf; marginals only, thr 2e-2).
//   - sampling: lane p runs sample p. li1 static-10 flat (this round),
//     li2/li3 static unrolled, li4 draws only for c==1 pairs.
//     All skipped draws are infeasible (-1e10 can't win) or argmax-of-one =>
//     bitwise-identical samples (PRNG + pruning verified rounds 1-15).

__host__ __device__ __forceinline__ void tf2x32(uint32_t k0, uint32_t k1,
                                                uint32_t x0, uint32_t x1,
                                                uint32_t& y0, uint32_t& y1) {
  const uint32_t ks[3] = {k0, k1, k0 ^ k1 ^ 0x1BD11BDAu};
  x0 += ks[0]; x1 += ks[1];
  const int R0[4] = {13, 15, 26, 6};
  const int R1[4] = {17, 29, 16, 24};
#pragma unroll
  for (int i = 0; i < 5; ++i) {
    const int* R = (i & 1) ? R1 : R0;
#pragma unroll
    for (int rr = 0; rr < 4; ++rr) {
      x0 += x1;
      x1 = (x1 << R[rr]) | (x1 >> (32 - R[rr]));
      x1 ^= x0;
    }
    x0 += ks[(i + 1) % 3];
    x1 += ks[(i + 2) % 3] + (uint32_t)(i + 1);
  }
  y0 = x0; y1 = x1;
}

struct TFKeys { uint32_t v[10]; };

// Exact gumbel (OCML logf) — must stay bit-identical to JAX reference.
__device__ __forceinline__ float gumbel_draw(uint32_t sk0, uint32_t sk1,
                                             uint32_t f) {
  uint32_t y0, y1;
  tf2x32(sk0, sk1, 0u, f, y0, y1);
  uint32_t bits = y0 ^ y1;
  uint32_t fb = (bits >> 9) | 0x3f800000u;
  float u = __uint_as_float(fb) - 1.0f;
  const float tiny = 1.17549435e-38f;
  float rr = fmaxf(tiny, u + tiny);
  return -logf(-logf(rr));
}

template<bool FAST> __device__ __forceinline__ float expT(float x) {
  return FAST ? __expf(x) : expf(x);
}
template<bool FAST> __device__ __forceinline__ float logT(float x) {
  return FAST ? __logf(x) : logf(x);
}

// o[m] = logsumexp_j aL[j] + aR[m-j] over in-support j, ascending-j sum.
// LS: last output is a single-term lse -> exact direct sum.
// 2-term m: s = expT(fmin-fmax)+1.0f — bitwise identical (expf(0)==1.0f
// exact; single IEEE add is commutative). All branches compile-time.
template<int SIN, int SOUT, bool FAST, bool LS>
__device__ __forceinline__ void conv_level(const float (&aL)[SIN],
                                           const float (&aR)[SIN],
                                           float (&o)[SOUT]) {
#pragma unroll
  for (int m = 1; m < SOUT; ++m) {
    if (LS && m == SOUT - 1) { o[m] = aL[SIN - 1] + aR[SIN - 1]; continue; }
    const int jlo = (m - (SIN - 1) > 0) ? (m - (SIN - 1)) : 0;
    const int jhi = (m < SIN - 1) ? m : (SIN - 1);
    if (jhi - jlo == 1) {
      float ta = aL[jlo] + aR[m - jlo];
      float tb = aL[jhi] + aR[m - jhi];
      float amax = fmaxf(ta, tb);
      o[m] = logT<FAST>(expT<FAST>(fminf(ta, tb) - amax) + 1.0f) + amax;
      continue;
    }
    float t[SIN];
#pragma unroll
    for (int j = 0; j < SIN; ++j)
      if (j >= jlo && j <= jhi) t[j] = aL[j] + aR[m - j];
    float amax = t[jlo];
#pragma unroll
    for (int j = 0; j < SIN; ++j)
      if (j > jlo && j <= jhi) amax = fmaxf(amax, t[j]);
    float s = 0.0f;
#pragma unroll
    for (int j = 0; j < SIN; ++j)
      if (j >= jlo && j <= jhi) s += expT<FAST>(t[j] - amax);
    o[m] = logT<FAST>(s) + amax;
  }
}

// eo[m] = logsumexp_{j=max(0,m-SSIB+1)..m} ein[j] + sib[m-j]
// 1-term m (m==jlo): o = t[jlo] (exp(0)==1, log(1)==0 exact).
// 2-term m: min/max trick as in conv_level.
template<int SSIB, int MLO, int MHI, bool FAST>
__device__ __forceinline__ void ext_level(const float (&ein)[8],
                                          const float* sib, float (&eo)[8]) {
#pragma unroll
  for (int m = MLO; m <= MHI; ++m) {
    const int jlo = (m - (SSIB - 1) > 0) ? (m - (SSIB - 1)) : 0;
    if (m == jlo) { eo[m] = ein[jlo] + sib[m - jlo]; continue; }
    if (m - jlo == 1) {
      float ta = ein[jlo] + sib[m - jlo];
      float tb = ein[m] + sib[0];
      float amax = fmaxf(ta, tb);
      eo[m] = logT<FAST>(expT<FAST>(fminf(ta, tb) - amax) + 1.0f) + amax;
      continue;
    }
    float t[8];
#pragma unroll
    for (int j = 0; j < 8; ++j)
      if (j >= jlo && j <= m) t[j] = ein[j] + sib[m - j];
    float amax = t[jlo];
#pragma unroll
    for (int j = 0; j < 8; ++j)
      if (j > jlo && j <= m) amax = fmaxf(amax, t[j]);
    float s = 0.0f;
#pragma unroll
    for (int j = 0; j < 8; ++j)
      if (j >= jlo && j <= m) s += expT<FAST>(t[j] - amax);
    eo[m] = logT<FAST>(s) + amax;
  }
}

// LDS entry map (stride 32 over r; bank = r%32 -> uniform-entry access is
// 32 banks x 2-way broadcast; divergent-entry access stays in own bank with
// at most 2-way pair alias = free):
//  theta col c        : 0..31
//  L1 m=1, node n1    : 32 + n1   (n1 0..15)
//  L1 m=2, node n1    : 48 + n1
//  L2 node n2, m=1..4 : 64 + n2*4 + (m-1)   (n2 0..7)
//  L3 node n3, m=1..8 : 96 + n3*8 + (m-1)   (n3 0..3)
#define ENT 128

__global__ __launch_bounds__(64, 2) void simple_sampler_kernel(
    const float* __restrict__ scores, float* __restrict__ out,
    int nnodes, TFKeys keys) {
  const int lane = threadIdx.x;
  const int p = lane & 1;        // sample id / subtree id for this lane
  const int r = lane >> 1;       // row-local 0..31
  const int row = blockIdx.x * 32 + r;
  const int node = row >> 3, e = row & 7;
  const int B = nnodes * 8;

  __shared__ float tab[ENT * 32];
#define L(E) tab[(E) * 32 + r]

  // ---- load own-half theta (16 cols), stash to LDS ----
  float th[16];
  const float* sc = scores + node * 256 + e + p * 128;
#pragma unroll
  for (int c = 0; c < 16; ++c) th[c] = sc[c * 8];
#pragma unroll
  for (int c = 0; c < 16; ++c) L(16 * p + c) = th[c];

  // ---- up pass, subtree n4 = p only (exact OCML) ----
  float l1r[8], th2r[8];
#pragma unroll
  for (int n1l = 0; n1l < 8; ++n1l) {
    float tL = th[2 * n1l], tR = th[2 * n1l + 1];
    float amax = fmaxf(tR, tL);              // t0 = thR (j=0), t1 = thL
    // expf(max-amax)==1.0f exactly; 2-term add commutative => bitwise same.
    float s = expf(fminf(tR, tL) - amax) + 1.0f;
    l1r[n1l] = logf(s) + amax;
    th2r[n1l] = tL + tR;                      // exact: logf(1.0f)==0.0f
    int n1 = 8 * p + n1l;
    L(32 + n1) = l1r[n1l];
    L(48 + n1) = th2r[n1l];
  }
  float l2r[4][5];
#pragma unroll
  for (int n2l = 0; n2l < 4; ++n2l) {
    float aL[3] = {0.0f, l1r[2 * n2l], th2r[2 * n2l]};
    float aR[3] = {0.0f, l1r[2 * n2l + 1], th2r[2 * n2l + 1]};
    float o5[5];
    conv_level<3, 5, false, true>(aL, aR, o5);
    l2r[n2l][0] = 0.0f;
    int n2 = 4 * p + n2l;
#pragma unroll
    for (int m = 1; m < 5; ++m) { l2r[n2l][m] = o5[m]; L(64 + n2 * 4 + m - 1) = o5[m]; }
  }
  float l3r[2][9];
#pragma unroll
  for (int n3l = 0; n3l < 2; ++n3l) {
    float o9[9];
    conv_level<5, 9, false, true>(l2r[2 * n3l], l2r[2 * n3l + 1], o9);
    l3r[n3l][0] = 0.0f;
    int n3 = 2 * p + n3l;
#pragma unroll
    for (int m = 1; m < 9; ++m) { l3r[n3l][m] = o9[m]; L(96 + n3 * 8 + m - 1) = o9[m]; }
  }

  // Pin ordering: all up-pass LDS writes precede all cross-half LDS reads.
  __builtin_amdgcn_wave_barrier();

  // ---- L4 node p in regs; exchange via shfl (no LDS, no barrier needed) ----
  float A0[9], A1[9];
  {
    float l4o[9];
    conv_level<9, 9, false, false>(l3r[0], l3r[1], l4o);
    A0[0] = 0.0f; A1[0] = 0.0f;
#pragma unroll
    for (int m = 1; m < 9; ++m) {
      float own = l4o[m];
      float oth = __shfl_xor(own, 1);
      A0[m] = p ? oth : own;
      A1[m] = p ? own : oth;
    }
  }

  // ---- logZ (marginals only -> fast) ----
  float logZ;
  {
    float tv[9];
#pragma unroll
    for (int j = 0; j < 9; ++j) tv[j] = A0[j] + A1[8 - j];
    float amax = tv[0];
#pragma unroll
    for (int j = 1; j < 9; ++j) amax = fmaxf(amax, tv[j]);
    float s = 0.0f;
#pragma unroll
    for (int j = 0; j < 9; ++j) s += __expf(tv[j] - amax);
    logZ = __logf(s) + amax;
  }

  // ---- down pass, subtrees n3 in {2p, 2p+1} (fast path; marginals only) ----
  {
    float e4v[8];
    e4v[0] = 0.0f;
#pragma unroll
    for (int m = 1; m < 8; ++m) e4v[m] = p ? A0[m] : A1[m];  // sibling of n4=p
    float* mb = out + 2 * B * 32 + node * 256 + e;
#pragma unroll
    for (int n3l = 0; n3l < 2; ++n3l) {
      float e3[8];
      ext_level<9, 0, 7, true>(e4v, l3r[n3l ^ 1], e3);
#pragma unroll
      for (int c2 = 0; c2 < 2; ++c2) {
        const int n2l = 2 * n3l + c2;
        float e2v[8];
        ext_level<5, 4, 7, true>(e3, l2r[n2l ^ 1], e2v);
#pragma unroll
        for (int c1i = 0; c1i < 2; ++c1i) {
          const int n1l = 2 * n2l + c1i;
          float sib1[3] = {0.0f, l1r[n1l ^ 1], th2r[n1l ^ 1]};
          float e1m[8];
          ext_level<3, 6, 7, true>(e2v, sib1, e1m);
          const int colL = 16 * p + 2 * n1l;
          {
            float t6 = e1m[6] + th[2 * n1l + 1];
            float t7 = e1m[7];
            float amax = fmaxf(t6, t7);
            float s = __expf(fminf(t6, t7) - amax) + 1.0f;
            mb[colL * 8] = __expf((th[2 * n1l] + (__logf(s) + amax)) - logZ);
          }
          {
            float t6 = e1m[6] + th[2 * n1l];
            float t7 = e1m[7];
            float amax = fmaxf(t6, t7);
            float s = __expf(fminf(t6, t7) - amax) + 1.0f;
            mb[(colL + 1) * 8] = __expf((th[2 * n1l + 1] + (__logf(s) + amax)) - logZ);
          }
        }
      }
    }
  }

  // ---- top-down sampling, sample s = p (bit-exact path) ----
  const uint32_t t9 = (uint32_t)(p * B + row) * 9u;
  int c0, c1;
  {  // root, c = 8, static (A0/A1 regs)
    float best = 0.0f; int bj = 0;
#pragma unroll
    for (int j = 0; j < 9; ++j) {
      float g = gumbel_draw(keys.v[0], keys.v[1], t9 + (uint32_t)j);
      float v = (A0[j] + A1[8 - j]) + g;
      if (j == 0) { best = v; } else if (v > best) { best = v; bj = j; }
    }
    c0 = bj; c1 = 8 - bj;
  }
  int c1v[4];
  {  // li1: static 10 slots with live guard (tot in {9,10}; wave cost was
     // already wave-max(tot)=10 via exec-masking -> zero added work, full
     // ILP across 10 independent draws). Dead slot t=9@tot=9 reads
     // in-bounds garbage (<=L(120) < ENT=128) and never updates.
    const int n0 = c0 ? c0 + 1 : 0;
    const int n1c = c1 ? c1 + 1 : 0;
    const int tot = n0 + n1c;
    float b0 = -3.0e38f, b1 = -3.0e38f;
    int j0 = 0, j1 = 0;
#pragma unroll
    for (int t = 0; t < 10; ++t) {
      const bool live = (t < tot);
      const bool is1 = (t >= n0);
      const int j = is1 ? (t - n0) : t;
      const int c = is1 ? c1 : c0;
      const int i = is1 ? 1 : 0;
      const int idx = c - j;
      float a = (j == 0) ? 0.0f : L(96 + 16 * i + j - 1);
      float b = (idx == 0) ? 0.0f : L(96 + 16 * i + 8 + idx - 1);
      float g = gumbel_draw(keys.v[2], keys.v[3],
                            2u * t9 + (uint32_t)(9 * i + j));
      float v = (a + b) + g;
      if (live && is1)  { if (v > b1) { b1 = v; j1 = j; } }
      if (live && !is1) { if (v > b0) { b0 = v; j0 = j; } }
    }
    c1v[0] = j0; c1v[1] = c0 - j0; c1v[2] = j1; c1v[3] = c1 - j1;
  }
  uint32_t pk2 = 0;
  {  // li2: 4 tasks, J=5 static with validity guard (low overhead per draw)
#pragma unroll
    for (int i = 0; i < 4; ++i) {
      int c = c1v[i];
      float best = -3.0e38f; int bj2 = 0;
#pragma unroll
      for (int j = 0; j < 5; ++j) {
        float g = gumbel_draw(keys.v[4], keys.v[5],
                              4u * t9 + (uint32_t)(i * 9 + j));
        int idx = c - j;
        int cl = min(max(idx, 1), 4);
        float b = L(64 + (2 * i + 1) * 4 + cl - 1);
        float bf = (idx == 0) ? 0.0f : b;
        float a = (j == 0) ? 0.0f : L(64 + (2 * i) * 4 + j - 1);
        float v = (a + bf) + g;
        if (idx >= 0 && idx <= 4 && v > best) { best = v; bj2 = j; }
      }
      pk2 |= ((uint32_t)bj2 << (8 * i)) | ((uint32_t)(c - bj2) << (8 * i + 4));
    }
  }
  uint64_t pk64 = 0;
  {  // li3: 8 tasks, J=3 static with validity guard
    const uint32_t sk0 = keys.v[6], sk1 = keys.v[7];
    const uint32_t fb0 = 8u * t9;
#pragma unroll 2
    for (int i = 0; i < 8; ++i) {
      int c = (int)((pk2 >> (4 * i)) & 15u);
      float aL1 = L(32 + 2 * i), aL2 = L(48 + 2 * i);
      float bR1 = L(32 + 2 * i + 1), bR2 = L(48 + 2 * i + 1);
      uint32_t fb = fb0 + (uint32_t)(i * 9);
      float best = -3.0e38f; int bj3 = 0;
#pragma unroll
      for (int j = 0; j < 3; ++j) {
        float g = gumbel_draw(sk0, sk1, fb + (uint32_t)j);
        int idx = c - j;
        float bf = (idx == 1) ? bR1 : ((idx == 2) ? bR2 : 0.0f);
        float af = (j == 0) ? 0.0f : ((j == 1) ? aL1 : aL2);
        float v = (af + bf) + g;
        if (idx >= 0 && idx <= 2 && v > best) { best = v; bj3 = j; }
      }
      pk64 |= ((uint64_t)(uint32_t)bj3 << (8 * i)) |
              ((uint64_t)(uint32_t)(c - bj3) << (8 * i + 4));
    }
  }
  {  // li4: draws ONLY for c==1 leaf pairs (c=0 -> bj=0, c=2 -> bj=1)
    const uint32_t sk0 = keys.v[8], sk1 = keys.v[9];
    const uint32_t fb0 = 16u * t9;
    float* bs = out + p * (B * 32) + node * 256 + e;
    uint64_t lst = 0; int m4 = 0;
#pragma unroll
    for (int i = 0; i < 16; ++i) {
      int c = (int)((uint32_t)(pk64 >> (4 * i)) & 15u);
      if (c == 1) {
        lst |= ((uint64_t)(uint32_t)i) << (4 * m4);
        ++m4;
      } else {
        int bj = c >> 1;                        // 0->0, 2->1
        bs[16 * i] = (float)bj;
        bs[16 * i + 8] = (float)(c - bj);
      }
    }
    for (int tt = 0; tt < m4; ++tt) {
      int i = (int)((lst >> (4 * tt)) & 15u);
      float thL = L(2 * i);
      float thR = L(2 * i + 1);
      uint32_t fb = fb0 + (uint32_t)(i * 9);
      float g0 = gumbel_draw(sk0, sk1, fb);       // j=0: 0 + thR
      float g1 = gumbel_draw(sk0, sk1, fb + 1u);  // j=1: thL + 0
      int bj = ((thL + g1) > (thR + g0)) ? 1 : 0; // first-max: strict >
      bs[16 * i] = (float)bj;
      bs[16 * i + 8] = (float)(1 - bj);
    }
  }
#undef L
}

extern "C" void kernel_launch(void* const* d_in, const int* in_sizes, int n_in,
                              void* d_out, int out_size, void* d_ws, size_t ws_size,
                              hipStream_t stream) {
  const float* scores = (const float*)d_in[0];
  float* out = (float*)d_out;
  const int nnodes = in_sizes[0] / (32 * 8);   // 8192
  const int B = nnodes * 8;                    // 65536 rows

  // key = jax.random.key(42); per level: key, sub = split(key)
  // (partitionable threefry: new = tf(key,(0,0)), sub = tf(key,(0,1)))
  TFKeys K;
  uint32_t k0 = 0u, k1 = 42u;
  for (int t = 0; t < 5; ++t) {
    uint32_t n0, n1, s0, s1;
    tf2x32(k0, k1, 0u, 0u, n0, n1);
    tf2x32(k0, k1, 0u, 1u, s0, s1);
    K.v[2 * t] = s0; K.v[2 * t + 1] = s1;
    k0 = n0; k1 = n1;
  }

  dim3 grid((unsigned)(B / 32)), block(64);
  hipLaunchKernelGGL(simple_sampler_kernel, grid, block, 0, stream,
                     scores, out, nnodes, K);
}

// Round 8
// 110.025 us; speedup vs baseline: 1.1082x; 1.0114x over previous
//
#include <hip/hip_runtime.h>
#include <stdint.h>

// Exact k-subset sampler, pair-per-row layout, zero __syncthreads.
// R17 = R16 + li4 STATIC-8 + li3 FULL UNROLL (ILP mechanism, 3rd application).
// R16 post-mortem: li1 static unroll won as modeled (61.3 -> 58.8us, busy
// 47.2 -> 45.0us). Mechanism confirmed: static unroll at equal wave-max
// cost converts serial draw chains into pipelined independent draws.
//   - li4: sum of leaf-pair counts = k = 8 => m4 (# of c==1 pairs) <= 8,
//     and wave-max(m4) ~ 8 typically. Static 8 slots, live=(tt<m4) guard:
//     dead slots decode nibble 0, read L(0)/L(1) (in-bounds), waste a draw,
//     skip the store. Wave cost unchanged; 16 logf-chains now ILP'd.
//   - li3: #pragma unroll 2 -> full (8 tasks x 3 draws in flight; VGPR
//     headroom 256 at 2 waves/EU, was 68).
// History: R10 4-lane +3.5us; R11 m-split +2.6us; R12 noinline +6.4us;
// R13 pair-compaction +3.4us; R15 2-term lse trims -0.7us; R16 li1 static
// unroll -2.5us. Lesson: R9 2-lane structure + static draws + micro-trims.
// R15 trims (bitwise-identical: IEEE add commutative, expf(0)==1.0f exact,
// logf(1)==0 exact): 2-term lse s = expT(fmin-fmax)+1.0f everywhere;
// ext_level 1-term m==jlo direct. Single-term conv outputs as direct sums.
// Layout (wave = 32 rows x 2 lanes, r = lane>>1, p = lane&1):
//   - up-pass split by p (exact OCML); L4 exchanged via shfl_xor (no LDS).
//   - down-pass split by p (fast __expf/__logf; marginals only, thr 2e-2).
//   - sampling: lane p runs sample p. li1 static-10 flat, li2 static 4x5,
//     li3 static 8x3 (full), li4 static-8 (c==1 pairs only).
//     All skipped draws are infeasible (-1e10 can't win) or argmax-of-one =>
//     bitwise-identical samples (PRNG + pruning verified rounds 1-16).

__host__ __device__ __forceinline__ void tf2x32(uint32_t k0, uint32_t k1,
                                                uint32_t x0, uint32_t x1,
                                                uint32_t& y0, uint32_t& y1) {
  const uint32_t ks[3] = {k0, k1, k0 ^ k1 ^ 0x1BD11BDAu};
  x0 += ks[0]; x1 += ks[1];
  const int R0[4] = {13, 15, 26, 6};
  const int R1[4] = {17, 29, 16, 24};
#pragma unroll
  for (int i = 0; i < 5; ++i) {
    const int* R = (i & 1) ? R1 : R0;
#pragma unroll
    for (int rr = 0; rr < 4; ++rr) {
      x0 += x1;
      x1 = (x1 << R[rr]) | (x1 >> (32 - R[rr]));
      x1 ^= x0;
    }
    x0 += ks[(i + 1) % 3];
    x1 += ks[(i + 2) % 3] + (uint32_t)(i + 1);
  }
  y0 = x0; y1 = x1;
}

struct TFKeys { uint32_t v[10]; };

// Exact gumbel (OCML logf) — must stay bit-identical to JAX reference.
__device__ __forceinline__ float gumbel_draw(uint32_t sk0, uint32_t sk1,
                                             uint32_t f) {
  uint32_t y0, y1;
  tf2x32(sk0, sk1, 0u, f, y0, y1);
  uint32_t bits = y0 ^ y1;
  uint32_t fb = (bits >> 9) | 0x3f800000u;
  float u = __uint_as_float(fb) - 1.0f;
  const float tiny = 1.17549435e-38f;
  float rr = fmaxf(tiny, u + tiny);
  return -logf(-logf(rr));
}

template<bool FAST> __device__ __forceinline__ float expT(float x) {
  return FAST ? __expf(x) : expf(x);
}
template<bool FAST> __device__ __forceinline__ float logT(float x) {
  return FAST ? __logf(x) : logf(x);
}

// o[m] = logsumexp_j aL[j] + aR[m-j] over in-support j, ascending-j sum.
// LS: last output is a single-term lse -> exact direct sum.
// 2-term m: s = expT(fmin-fmax)+1.0f — bitwise identical (expf(0)==1.0f
// exact; single IEEE add is commutative). All branches compile-time.
template<int SIN, int SOUT, bool FAST, bool LS>
__device__ __forceinline__ void conv_level(const float (&aL)[SIN],
                                           const float (&aR)[SIN],
                                           float (&o)[SOUT]) {
#pragma unroll
  for (int m = 1; m < SOUT; ++m) {
    if (LS && m == SOUT - 1) { o[m] = aL[SIN - 1] + aR[SIN - 1]; continue; }
    const int jlo = (m - (SIN - 1) > 0) ? (m - (SIN - 1)) : 0;
    const int jhi = (m < SIN - 1) ? m : (SIN - 1);
    if (jhi - jlo == 1) {
      float ta = aL[jlo] + aR[m - jlo];
      float tb = aL[jhi] + aR[m - jhi];
      float amax = fmaxf(ta, tb);
      o[m] = logT<FAST>(expT<FAST>(fminf(ta, tb) - amax) + 1.0f) + amax;
      continue;
    }
    float t[SIN];
#pragma unroll
    for (int j = 0; j < SIN; ++j)
      if (j >= jlo && j <= jhi) t[j] = aL[j] + aR[m - j];
    float amax = t[jlo];
#pragma unroll
    for (int j = 0; j < SIN; ++j)
      if (j > jlo && j <= jhi) amax = fmaxf(amax, t[j]);
    float s = 0.0f;
#pragma unroll
    for (int j = 0; j < SIN; ++j)
      if (j >= jlo && j <= jhi) s += expT<FAST>(t[j] - amax);
    o[m] = logT<FAST>(s) + amax;
  }
}

// eo[m] = logsumexp_{j=max(0,m-SSIB+1)..m} ein[j] + sib[m-j]
// 1-term m (m==jlo): o = t[jlo] (exp(0)==1, log(1)==0 exact).
// 2-term m: min/max trick as in conv_level.
template<int SSIB, int MLO, int MHI, bool FAST>
__device__ __forceinline__ void ext_level(const float (&ein)[8],
                                          const float* sib, float (&eo)[8]) {
#pragma unroll
  for (int m = MLO; m <= MHI; ++m) {
    const int jlo = (m - (SSIB - 1) > 0) ? (m - (SSIB - 1)) : 0;
    if (m == jlo) { eo[m] = ein[jlo] + sib[m - jlo]; continue; }
    if (m - jlo == 1) {
      float ta = ein[jlo] + sib[m - jlo];
      float tb = ein[m] + sib[0];
      float amax = fmaxf(ta, tb);
      eo[m] = logT<FAST>(expT<FAST>(fminf(ta, tb) - amax) + 1.0f) + amax;
      continue;
    }
    float t[8];
#pragma unroll
    for (int j = 0; j < 8; ++j)
      if (j >= jlo && j <= m) t[j] = ein[j] + sib[m - j];
    float amax = t[jlo];
#pragma unroll
    for (int j = 0; j < 8; ++j)
      if (j > jlo && j <= m) amax = fmaxf(amax, t[j]);
    float s = 0.0f;
#pragma unroll
    for (int j = 0; j < 8; ++j)
      if (j >= jlo && j <= m) s += expT<FAST>(t[j] - amax);
    eo[m] = logT<FAST>(s) + amax;
  }
}

// LDS entry map (stride 32 over r; bank = r%32 -> uniform-entry access is
// 32 banks x 2-way broadcast; divergent-entry access stays in own bank with
// at most 2-way pair alias = free):
//  theta col c        : 0..31
//  L1 m=1, node n1    : 32 + n1   (n1 0..15)
//  L1 m=2, node n1    : 48 + n1
//  L2 node n2, m=1..4 : 64 + n2*4 + (m-1)   (n2 0..7)
//  L3 node n3, m=1..8 : 96 + n3*8 + (m-1)   (n3 0..3)
#define ENT 128

__global__ __launch_bounds__(64, 2) void simple_sampler_kernel(
    const float* __restrict__ scores, float* __restrict__ out,
    int nnodes, TFKeys keys) {
  const int lane = threadIdx.x;
  const int p = lane & 1;        // sample id / subtree id for this lane
  const int r = lane >> 1;       // row-local 0..31
  const int row = blockIdx.x * 32 + r;
  const int node = row >> 3, e = row & 7;
  const int B = nnodes * 8;

  __shared__ float tab[ENT * 32];
#define L(E) tab[(E) * 32 + r]

  // ---- load own-half theta (16 cols), stash to LDS ----
  float th[16];
  const float* sc = scores + node * 256 + e + p * 128;
#pragma unroll
  for (int c = 0; c < 16; ++c) th[c] = sc[c * 8];
#pragma unroll
  for (int c = 0; c < 16; ++c) L(16 * p + c) = th[c];

  // ---- up pass, subtree n4 = p only (exact OCML) ----
  float l1r[8], th2r[8];
#pragma unroll
  for (int n1l = 0; n1l < 8; ++n1l) {
    float tL = th[2 * n1l], tR = th[2 * n1l + 1];
    float amax = fmaxf(tR, tL);              // t0 = thR (j=0), t1 = thL
    // expf(max-amax)==1.0f exactly; 2-term add commutative => bitwise same.
    float s = expf(fminf(tR, tL) - amax) + 1.0f;
    l1r[n1l] = logf(s) + amax;
    th2r[n1l] = tL + tR;                      // exact: logf(1.0f)==0.0f
    int n1 = 8 * p + n1l;
    L(32 + n1) = l1r[n1l];
    L(48 + n1) = th2r[n1l];
  }
  float l2r[4][5];
#pragma unroll
  for (int n2l = 0; n2l < 4; ++n2l) {
    float aL[3] = {0.0f, l1r[2 * n2l], th2r[2 * n2l]};
    float aR[3] = {0.0f, l1r[2 * n2l + 1], th2r[2 * n2l + 1]};
    float o5[5];
    conv_level<3, 5, false, true>(aL, aR, o5);
    l2r[n2l][0] = 0.0f;
    int n2 = 4 * p + n2l;
#pragma unroll
    for (int m = 1; m < 5; ++m) { l2r[n2l][m] = o5[m]; L(64 + n2 * 4 + m - 1) = o5[m]; }
  }
  float l3r[2][9];
#pragma unroll
  for (int n3l = 0; n3l < 2; ++n3l) {
    float o9[9];
    conv_level<5, 9, false, true>(l2r[2 * n3l], l2r[2 * n3l + 1], o9);
    l3r[n3l][0] = 0.0f;
    int n3 = 2 * p + n3l;
#pragma unroll
    for (int m = 1; m < 9; ++m) { l3r[n3l][m] = o9[m]; L(96 + n3 * 8 + m - 1) = o9[m]; }
  }

  // Pin ordering: all up-pass LDS writes precede all cross-half LDS reads.
  __builtin_amdgcn_wave_barrier();

  // ---- L4 node p in regs; exchange via shfl (no LDS, no barrier needed) ----
  float A0[9], A1[9];
  {
    float l4o[9];
    conv_level<9, 9, false, false>(l3r[0], l3r[1], l4o);
    A0[0] = 0.0f; A1[0] = 0.0f;
#pragma unroll
    for (int m = 1; m < 9; ++m) {
      float own = l4o[m];
      float oth = __shfl_xor(own, 1);
      A0[m] = p ? oth : own;
      A1[m] = p ? own : oth;
    }
  }

  // ---- logZ (marginals only -> fast) ----
  float logZ;
  {
    float tv[9];
#pragma unroll
    for (int j = 0; j < 9; ++j) tv[j] = A0[j] + A1[8 - j];
    float amax = tv[0];
#pragma unroll
    for (int j = 1; j < 9; ++j) amax = fmaxf(amax, tv[j]);
    float s = 0.0f;
#pragma unroll
    for (int j = 0; j < 9; ++j) s += __expf(tv[j] - amax);
    logZ = __logf(s) + amax;
  }

  // ---- down pass, subtrees n3 in {2p, 2p+1} (fast path; marginals only) ----
  {
    float e4v[8];
    e4v[0] = 0.0f;
#pragma unroll
    for (int m = 1; m < 8; ++m) e4v[m] = p ? A0[m] : A1[m];  // sibling of n4=p
    float* mb = out + 2 * B * 32 + node * 256 + e;
#pragma unroll
    for (int n3l = 0; n3l < 2; ++n3l) {
      float e3[8];
      ext_level<9, 0, 7, true>(e4v, l3r[n3l ^ 1], e3);
#pragma unroll
      for (int c2 = 0; c2 < 2; ++c2) {
        const int n2l = 2 * n3l + c2;
        float e2v[8];
        ext_level<5, 4, 7, true>(e3, l2r[n2l ^ 1], e2v);
#pragma unroll
        for (int c1i = 0; c1i < 2; ++c1i) {
          const int n1l = 2 * n2l + c1i;
          float sib1[3] = {0.0f, l1r[n1l ^ 1], th2r[n1l ^ 1]};
          float e1m[8];
          ext_level<3, 6, 7, true>(e2v, sib1, e1m);
          const int colL = 16 * p + 2 * n1l;
          {
            float t6 = e1m[6] + th[2 * n1l + 1];
            float t7 = e1m[7];
            float amax = fmaxf(t6, t7);
            float s = __expf(fminf(t6, t7) - amax) + 1.0f;
            mb[colL * 8] = __expf((th[2 * n1l] + (__logf(s) + amax)) - logZ);
          }
          {
            float t6 = e1m[6] + th[2 * n1l];
            float t7 = e1m[7];
            float amax = fmaxf(t6, t7);
            float s = __expf(fminf(t6, t7) - amax) + 1.0f;
            mb[(colL + 1) * 8] = __expf((th[2 * n1l + 1] + (__logf(s) + amax)) - logZ);
          }
        }
      }
    }
  }

  // ---- top-down sampling, sample s = p (bit-exact path) ----
  const uint32_t t9 = (uint32_t)(p * B + row) * 9u;
  int c0, c1;
  {  // root, c = 8, static (A0/A1 regs)
    float best = 0.0f; int bj = 0;
#pragma unroll
    for (int j = 0; j < 9; ++j) {
      float g = gumbel_draw(keys.v[0], keys.v[1], t9 + (uint32_t)j);
      float v = (A0[j] + A1[8 - j]) + g;
      if (j == 0) { best = v; } else if (v > best) { best = v; bj = j; }
    }
    c0 = bj; c1 = 8 - bj;
  }
  int c1v[4];
  {  // li1: static 10 slots with live guard (tot in {9,10}; wave cost was
     // already wave-max(tot)=10 via exec-masking -> zero added work, full
     // ILP across 10 independent draws). Dead slot t=9@tot=9 reads
     // in-bounds garbage (<=L(120) < ENT=128) and never updates.
    const int n0 = c0 ? c0 + 1 : 0;
    const int n1c = c1 ? c1 + 1 : 0;
    const int tot = n0 + n1c;
    float b0 = -3.0e38f, b1 = -3.0e38f;
    int j0 = 0, j1 = 0;
#pragma unroll
    for (int t = 0; t < 10; ++t) {
      const bool live = (t < tot);
      const bool is1 = (t >= n0);
      const int j = is1 ? (t - n0) : t;
      const int c = is1 ? c1 : c0;
      const int i = is1 ? 1 : 0;
      const int idx = c - j;
      float a = (j == 0) ? 0.0f : L(96 + 16 * i + j - 1);
      float b = (idx == 0) ? 0.0f : L(96 + 16 * i + 8 + idx - 1);
      float g = gumbel_draw(keys.v[2], keys.v[3],
                            2u * t9 + (uint32_t)(9 * i + j));
      float v = (a + b) + g;
      if (live && is1)  { if (v > b1) { b1 = v; j1 = j; } }
      if (live && !is1) { if (v > b0) { b0 = v; j0 = j; } }
    }
    c1v[0] = j0; c1v[1] = c0 - j0; c1v[2] = j1; c1v[3] = c1 - j1;
  }
  uint32_t pk2 = 0;
  {  // li2: 4 tasks, J=5 static with validity guard (low overhead per draw)
#pragma unroll
    for (int i = 0; i < 4; ++i) {
      int c = c1v[i];
      float best = -3.0e38f; int bj2 = 0;
#pragma unroll
      for (int j = 0; j < 5; ++j) {
        float g = gumbel_draw(keys.v[4], keys.v[5],
                              4u * t9 + (uint32_t)(i * 9 + j));
        int idx = c - j;
        int cl = min(max(idx, 1), 4);
        float b = L(64 + (2 * i + 1) * 4 + cl - 1);
        float bf = (idx == 0) ? 0.0f : b;
        float a = (j == 0) ? 0.0f : L(64 + (2 * i) * 4 + j - 1);
        float v = (a + bf) + g;
        if (idx >= 0 && idx <= 4 && v > best) { best = v; bj2 = j; }
      }
      pk2 |= ((uint32_t)bj2 << (8 * i)) | ((uint32_t)(c - bj2) << (8 * i + 4));
    }
  }
  uint64_t pk64 = 0;
  {  // li3: 8 tasks, J=3 static with validity guard; FULL unroll (R17) —
     // 24 independent draws in flight (was 2 tasks at a time).
    const uint32_t sk0 = keys.v[6], sk1 = keys.v[7];
    const uint32_t fb0 = 8u * t9;
#pragma unroll
    for (int i = 0; i < 8; ++i) {
      int c = (int)((pk2 >> (4 * i)) & 15u);
      float aL1 = L(32 + 2 * i), aL2 = L(48 + 2 * i);
      float bR1 = L(32 + 2 * i + 1), bR2 = L(48 + 2 * i + 1);
      uint32_t fb = fb0 + (uint32_t)(i * 9);
      float best = -3.0e38f; int bj3 = 0;
#pragma unroll
      for (int j = 0; j < 3; ++j) {
        float g = gumbel_draw(sk0, sk1, fb + (uint32_t)j);
        int idx = c - j;
        float bf = (idx == 1) ? bR1 : ((idx == 2) ? bR2 : 0.0f);
        float af = (j == 0) ? 0.0f : ((j == 1) ? aL1 : aL2);
        float v = (af + bf) + g;
        if (idx >= 0 && idx <= 2 && v > best) { best = v; bj3 = j; }
      }
      pk64 |= ((uint64_t)(uint32_t)bj3 << (8 * i)) |
              ((uint64_t)(uint32_t)(c - bj3) << (8 * i + 4));
    }
  }
  {  // li4: draws ONLY for c==1 leaf pairs (c=0 -> bj=0, c=2 -> bj=1).
     // R17: static 8 slots (m4 <= 8 because sum of leaf-pair counts = 8);
     // live=(tt<m4) guard; dead slots decode nibble 0 -> read L(0)/L(1)
     // (in-bounds), waste a draw, skip the store. Wave cost unchanged
     // (wave-max(m4)~8), 16 logf chains now fully ILP'd.
    const uint32_t sk0 = keys.v[8], sk1 = keys.v[9];
    const uint32_t fb0 = 16u * t9;
    float* bs = out + p * (B * 32) + node * 256 + e;
    uint32_t lst = 0; int m4 = 0;
#pragma unroll
    for (int i = 0; i < 16; ++i) {
      int c = (int)((uint32_t)(pk64 >> (4 * i)) & 15u);
      if (c == 1) {
        lst |= ((uint32_t)i) << (4 * m4);
        ++m4;
      } else {
        int bj = c >> 1;                        // 0->0, 2->1
        bs[16 * i] = (float)bj;
        bs[16 * i + 8] = (float)(c - bj);
      }
    }
#pragma unroll
    for (int tt = 0; tt < 8; ++tt) {
      const bool live = (tt < m4);
      int i = (int)((lst >> (4 * tt)) & 15u);
      float thL = L(2 * i);
      float thR = L(2 * i + 1);
      uint32_t fb = fb0 + (uint32_t)(i * 9);
      float g0 = gumbel_draw(sk0, sk1, fb);       // j=0: 0 + thR
      float g1 = gumbel_draw(sk0, sk1, fb + 1u);  // j=1: thL + 0
      int bj = ((thL + g1) > (thR + g0)) ? 1 : 0; // first-max: strict >
      if (live) {
        bs[16 * i] = (float)bj;
        bs[16 * i + 8] = (float)(1 - bj);
      }
    }
  }
#undef L
}

extern "C" void kernel_launch(void* const* d_in, const int* in_sizes, int n_in,
                              void* d_out, int out_size, void* d_ws, size_t ws_size,
                              hipStream_t stream) {
  const float* scores = (const float*)d_in[0];
  float* out = (float*)d_out;
  const int nnodes = in_sizes[0] / (32 * 8);   // 8192
  const int B = nnodes * 8;                    // 65536 rows

  // key = jax.random.key(42); per level: key, sub = split(key)
  // (partitionable threefry: new = tf(key,(0,0)), sub = tf(key,(0,1)))
  TFKeys K;
  uint32_t k0 = 0u, k1 = 42u;
  for (int t = 0; t < 5; ++t) {
    uint32_t n0, n1, s0, s1;
    tf2x32(k0, k1, 0u, 0u, n0, n1);
    tf2x32(k0, k1, 0u, 1u, s0, s1);
    K.v[2 * t] = s0; K.v[2 * t + 1] = s1;
    k0 = n0; k1 = n1;
  }

  dim3 grid((unsigned)(B / 32)), block(64);
  hipLaunchKernelGGL(simple_sampler_kernel, grid, block, 0, stream,
                     scores, out, nnodes, K);
}

// Round 9
// 107.209 us; speedup vs baseline: 1.1373x; 1.0263x over previous
//
#include <hip/hip_runtime.h>
#include <stdint.h>

// Exact k-subset sampler, pair-per-row layout, zero __syncthreads.
// R18 = R17 + PHASE INTERLEAVE (anti-lockstep) + tv reuse.
// R17 post-mortem: li4 static-8 + li3 full unroll won (58.8 -> 57.2us).
// Busy-work now ~42us but VALUBusy FELL to 73.5% -- with 2 identical waves
// per SIMD launched in lockstep, both hit the same dependency stalls at the
// same cycles (level-boundary waits in sampling; exp->sum->log chains in
// down-pass) -> SIMD idles 26%. The down-pass (float/exp pipes) and the
// sampling draws (int threefry + logf) are INDEPENDENT workloads with
// complementary pipe usage. R18 interleaves them at source level so the
// scheduler always sees both kinds of chains:
//   up-pass -> L4/tv/logZ -> ROOT DRAWS -> down(n3l=0) -> LI1 DRAWS ->
//   down(n3l=1) -> li2 -> li3 -> li4.
// All swaps are between provably independent blocks => bitwise identical.
// Rider: tv[j]=A0[j]+A1[8-j] computed once, reused by logZ AND root draw.
// History: R10 4-lane +3.5; R11 m-split +2.6; R12 noinline +6.4;
// R13 pair-compaction +3.4 (all vs contemporaries); R15 lse trims -0.7;
// R16 li1 static -2.5; R17 li4 static + li3 full -1.6. Mechanisms:
// static unroll at equal wave-max cost = free ILP; dynamic compaction loses.
// R15 trims (bitwise-identical: IEEE add commutative, expf(0)==1.0f exact,
// logf(1)==0 exact): 2-term lse s = expT(fmin-fmax)+1.0f everywhere;
// ext_level 1-term m==jlo direct. Single-term conv outputs as direct sums.
// Layout (wave = 32 rows x 2 lanes, r = lane>>1, p = lane&1):
//   - up-pass split by p (exact OCML); L4 exchanged via shfl_xor (no LDS).
//   - down-pass split by p (fast __expf/__logf; marginals only, thr 2e-2).
//   - sampling: lane p runs sample p. li1 static-10 flat, li2 static 4x5,
//     li3 static 8x3 (full), li4 static-8 (c==1 pairs only).
//     All skipped draws are infeasible (-1e10 can't win) or argmax-of-one =>
//     bitwise-identical samples (PRNG + pruning verified rounds 1-17).

__host__ __device__ __forceinline__ void tf2x32(uint32_t k0, uint32_t k1,
                                                uint32_t x0, uint32_t x1,
                                                uint32_t& y0, uint32_t& y1) {
  const uint32_t ks[3] = {k0, k1, k0 ^ k1 ^ 0x1BD11BDAu};
  x0 += ks[0]; x1 += ks[1];
  const int R0[4] = {13, 15, 26, 6};
  const int R1[4] = {17, 29, 16, 24};
#pragma unroll
  for (int i = 0; i < 5; ++i) {
    const int* R = (i & 1) ? R1 : R0;
#pragma unroll
    for (int rr = 0; rr < 4; ++rr) {
      x0 += x1;
      x1 = (x1 << R[rr]) | (x1 >> (32 - R[rr]));
      x1 ^= x0;
    }
    x0 += ks[(i + 1) % 3];
    x1 += ks[(i + 2) % 3] + (uint32_t)(i + 1);
  }
  y0 = x0; y1 = x1;
}

struct TFKeys { uint32_t v[10]; };

// Exact gumbel (OCML logf) — must stay bit-identical to JAX reference.
__device__ __forceinline__ float gumbel_draw(uint32_t sk0, uint32_t sk1,
                                             uint32_t f) {
  uint32_t y0, y1;
  tf2x32(sk0, sk1, 0u, f, y0, y1);
  uint32_t bits = y0 ^ y1;
  uint32_t fb = (bits >> 9) | 0x3f800000u;
  float u = __uint_as_float(fb) - 1.0f;
  const float tiny = 1.17549435e-38f;
  float rr = fmaxf(tiny, u + tiny);
  return -logf(-logf(rr));
}

template<bool FAST> __device__ __forceinline__ float expT(float x) {
  return FAST ? __expf(x) : expf(x);
}
template<bool FAST> __device__ __forceinline__ float logT(float x) {
  return FAST ? __logf(x) : logf(x);
}

// o[m] = logsumexp_j aL[j] + aR[m-j] over in-support j, ascending-j sum.
// LS: last output is a single-term lse -> exact direct sum.
// 2-term m: s = expT(fmin-fmax)+1.0f — bitwise identical (expf(0)==1.0f
// exact; single IEEE add is commutative). All branches compile-time.
template<int SIN, int SOUT, bool FAST, bool LS>
__device__ __forceinline__ void conv_level(const float (&aL)[SIN],
                                           const float (&aR)[SIN],
                                           float (&o)[SOUT]) {
#pragma unroll
  for (int m = 1; m < SOUT; ++m) {
    if (LS && m == SOUT - 1) { o[m] = aL[SIN - 1] + aR[SIN - 1]; continue; }
    const int jlo = (m - (SIN - 1) > 0) ? (m - (SIN - 1)) : 0;
    const int jhi = (m < SIN - 1) ? m : (SIN - 1);
    if (jhi - jlo == 1) {
      float ta = aL[jlo] + aR[m - jlo];
      float tb = aL[jhi] + aR[m - jhi];
      float amax = fmaxf(ta, tb);
      o[m] = logT<FAST>(expT<FAST>(fminf(ta, tb) - amax) + 1.0f) + amax;
      continue;
    }
    float t[SIN];
#pragma unroll
    for (int j = 0; j < SIN; ++j)
      if (j >= jlo && j <= jhi) t[j] = aL[j] + aR[m - j];
    float amax = t[jlo];
#pragma unroll
    for (int j = 0; j < SIN; ++j)
      if (j > jlo && j <= jhi) amax = fmaxf(amax, t[j]);
    float s = 0.0f;
#pragma unroll
    for (int j = 0; j < SIN; ++j)
      if (j >= jlo && j <= jhi) s += expT<FAST>(t[j] - amax);
    o[m] = logT<FAST>(s) + amax;
  }
}

// eo[m] = logsumexp_{j=max(0,m-SSIB+1)..m} ein[j] + sib[m-j]
// 1-term m (m==jlo): o = t[jlo] (exp(0)==1, log(1)==0 exact).
// 2-term m: min/max trick as in conv_level.
template<int SSIB, int MLO, int MHI, bool FAST>
__device__ __forceinline__ void ext_level(const float (&ein)[8],
                                          const float* sib, float (&eo)[8]) {
#pragma unroll
  for (int m = MLO; m <= MHI; ++m) {
    const int jlo = (m - (SSIB - 1) > 0) ? (m - (SSIB - 1)) : 0;
    if (m == jlo) { eo[m] = ein[jlo] + sib[m - jlo]; continue; }
    if (m - jlo == 1) {
      float ta = ein[jlo] + sib[m - jlo];
      float tb = ein[m] + sib[0];
      float amax = fmaxf(ta, tb);
      eo[m] = logT<FAST>(expT<FAST>(fminf(ta, tb) - amax) + 1.0f) + amax;
      continue;
    }
    float t[8];
#pragma unroll
    for (int j = 0; j < 8; ++j)
      if (j >= jlo && j <= m) t[j] = ein[j] + sib[m - j];
    float amax = t[jlo];
#pragma unroll
    for (int j = 0; j < 8; ++j)
      if (j > jlo && j <= m) amax = fmaxf(amax, t[j]);
    float s = 0.0f;
#pragma unroll
    for (int j = 0; j < 8; ++j)
      if (j >= jlo && j <= m) s += expT<FAST>(t[j] - amax);
    eo[m] = logT<FAST>(s) + amax;
  }
}

// LDS entry map (stride 32 over r; bank = r%32 -> uniform-entry access is
// 32 banks x 2-way broadcast; divergent-entry access stays in own bank with
// at most 2-way pair alias = free):
//  theta col c        : 0..31
//  L1 m=1, node n1    : 32 + n1   (n1 0..15)
//  L1 m=2, node n1    : 48 + n1
//  L2 node n2, m=1..4 : 64 + n2*4 + (m-1)   (n2 0..7)
//  L3 node n3, m=1..8 : 96 + n3*8 + (m-1)   (n3 0..3)
#define ENT 128

__global__ __launch_bounds__(64, 2) void simple_sampler_kernel(
    const float* __restrict__ scores, float* __restrict__ out,
    int nnodes, TFKeys keys) {
  const int lane = threadIdx.x;
  const int p = lane & 1;        // sample id / subtree id for this lane
  const int r = lane >> 1;       // row-local 0..31
  const int row = blockIdx.x * 32 + r;
  const int node = row >> 3, e = row & 7;
  const int B = nnodes * 8;

  __shared__ float tab[ENT * 32];
#define L(E) tab[(E) * 32 + r]

  // ---- load own-half theta (16 cols), stash to LDS ----
  float th[16];
  const float* sc = scores + node * 256 + e + p * 128;
#pragma unroll
  for (int c = 0; c < 16; ++c) th[c] = sc[c * 8];
#pragma unroll
  for (int c = 0; c < 16; ++c) L(16 * p + c) = th[c];

  // ---- up pass, subtree n4 = p only (exact OCML) ----
  float l1r[8], th2r[8];
#pragma unroll
  for (int n1l = 0; n1l < 8; ++n1l) {
    float tL = th[2 * n1l], tR = th[2 * n1l + 1];
    float amax = fmaxf(tR, tL);              // t0 = thR (j=0), t1 = thL
    // expf(max-amax)==1.0f exactly; 2-term add commutative => bitwise same.
    float s = expf(fminf(tR, tL) - amax) + 1.0f;
    l1r[n1l] = logf(s) + amax;
    th2r[n1l] = tL + tR;                      // exact: logf(1.0f)==0.0f
    int n1 = 8 * p + n1l;
    L(32 + n1) = l1r[n1l];
    L(48 + n1) = th2r[n1l];
  }
  float l2r[4][5];
#pragma unroll
  for (int n2l = 0; n2l < 4; ++n2l) {
    float aL[3] = {0.0f, l1r[2 * n2l], th2r[2 * n2l]};
    float aR[3] = {0.0f, l1r[2 * n2l + 1], th2r[2 * n2l + 1]};
    float o5[5];
    conv_level<3, 5, false, true>(aL, aR, o5);
    l2r[n2l][0] = 0.0f;
    int n2 = 4 * p + n2l;
#pragma unroll
    for (int m = 1; m < 5; ++m) { l2r[n2l][m] = o5[m]; L(64 + n2 * 4 + m - 1) = o5[m]; }
  }
  float l3r[2][9];
#pragma unroll
  for (int n3l = 0; n3l < 2; ++n3l) {
    float o9[9];
    conv_level<5, 9, false, true>(l2r[2 * n3l], l2r[2 * n3l + 1], o9);
    l3r[n3l][0] = 0.0f;
    int n3 = 2 * p + n3l;
#pragma unroll
    for (int m = 1; m < 9; ++m) { l3r[n3l][m] = o9[m]; L(96 + n3 * 8 + m - 1) = o9[m]; }
  }

  // Pin ordering: all up-pass LDS writes precede all cross-half LDS reads.
  __builtin_amdgcn_wave_barrier();

  // ---- L4 node p in regs; exchange via shfl (no LDS, no barrier needed) ----
  float A0[9], A1[9];
  {
    float l4o[9];
    conv_level<9, 9, false, false>(l3r[0], l3r[1], l4o);
    A0[0] = 0.0f; A1[0] = 0.0f;
#pragma unroll
    for (int m = 1; m < 9; ++m) {
      float own = l4o[m];
      float oth = __shfl_xor(own, 1);
      A0[m] = p ? oth : own;
      A1[m] = p ? own : oth;
    }
  }

  // ---- tv[j] = A0[j]+A1[8-j]: shared by logZ AND the root draw (R18) ----
  float tv[9];
#pragma unroll
  for (int j = 0; j < 9; ++j) tv[j] = A0[j] + A1[8 - j];
  float logZ;
  {
    float amax = tv[0];
#pragma unroll
    for (int j = 1; j < 9; ++j) amax = fmaxf(amax, tv[j]);
    float s = 0.0f;
#pragma unroll
    for (int j = 0; j < 9; ++j) s += __expf(tv[j] - amax);
    logZ = __logf(s) + amax;
  }

  const uint32_t t9 = (uint32_t)(p * B + row) * 9u;

  // ---- PHASE A: root draws (int/threefry + exact logf pipes) ----
  int c0, c1;
  {  // root, c = 8, static (tv regs)
    float best = 0.0f; int bj = 0;
#pragma unroll
    for (int j = 0; j < 9; ++j) {
      float g = gumbel_draw(keys.v[0], keys.v[1], t9 + (uint32_t)j);
      float v = tv[j] + g;
      if (j == 0) { best = v; } else if (v > best) { best = v; bj = j; }
    }
    c0 = bj; c1 = 8 - bj;
  }

  // ---- common down-pass state ----
  float e4v[8];
  e4v[0] = 0.0f;
#pragma unroll
  for (int m = 1; m < 8; ++m) e4v[m] = p ? A0[m] : A1[m];  // sibling of n4=p
  float* mb = out + 2 * B * 32 + node * 256 + e;

  // ---- PHASE B: down-pass chunk n3l=0 (float/exp pipes; independent of A) --
  {
    const int n3l = 0;
    float e3[8];
    ext_level<9, 0, 7, true>(e4v, l3r[n3l ^ 1], e3);
#pragma unroll
    for (int c2 = 0; c2 < 2; ++c2) {
      const int n2l = 2 * n3l + c2;
      float e2v[8];
      ext_level<5, 4, 7, true>(e3, l2r[n2l ^ 1], e2v);
#pragma unroll
      for (int c1i = 0; c1i < 2; ++c1i) {
        const int n1l = 2 * n2l + c1i;
        float sib1[3] = {0.0f, l1r[n1l ^ 1], th2r[n1l ^ 1]};
        float e1m[8];
        ext_level<3, 6, 7, true>(e2v, sib1, e1m);
        const int colL = 16 * p + 2 * n1l;
        {
          float t6 = e1m[6] + th[2 * n1l + 1];
          float t7 = e1m[7];
          float amax = fmaxf(t6, t7);
          float s = __expf(fminf(t6, t7) - amax) + 1.0f;
          mb[colL * 8] = __expf((th[2 * n1l] + (__logf(s) + amax)) - logZ);
        }
        {
          float t6 = e1m[6] + th[2 * n1l];
          float t7 = e1m[7];
          float amax = fmaxf(t6, t7);
          float s = __expf(fminf(t6, t7) - amax) + 1.0f;
          mb[(colL + 1) * 8] = __expf((th[2 * n1l + 1] + (__logf(s) + amax)) - logZ);
        }
      }
    }
  }

  // ---- PHASE C: li1 draws (needs only rootj + LDS L3; independent of B) ----
  int c1v[4];
  {  // li1: static 10 slots with live guard (tot in {9,10}; wave cost was
     // already wave-max(tot)=10 via exec-masking -> zero added work, full
     // ILP across 10 independent draws). Dead slot reads in-bounds garbage
     // and never updates.
    const int n0 = c0 ? c0 + 1 : 0;
    const int n1c = c1 ? c1 + 1 : 0;
    const int tot = n0 + n1c;
    float b0 = -3.0e38f, b1 = -3.0e38f;
    int j0 = 0, j1 = 0;
#pragma unroll
    for (int t = 0; t < 10; ++t) {
      const bool live = (t < tot);
      const bool is1 = (t >= n0);
      const int j = is1 ? (t - n0) : t;
      const int c = is1 ? c1 : c0;
      const int i = is1 ? 1 : 0;
      const int idx = c - j;
      float a = (j == 0) ? 0.0f : L(96 + 16 * i + j - 1);
      float b = (idx == 0) ? 0.0f : L(96 + 16 * i + 8 + idx - 1);
      float g = gumbel_draw(keys.v[2], keys.v[3],
                            2u * t9 + (uint32_t)(9 * i + j));
      float v = (a + b) + g;
      if (live && is1)  { if (v > b1) { b1 = v; j1 = j; } }
      if (live && !is1) { if (v > b0) { b0 = v; j0 = j; } }
    }
    c1v[0] = j0; c1v[1] = c0 - j0; c1v[2] = j1; c1v[3] = c1 - j1;
  }

  // ---- PHASE D: down-pass chunk n3l=1 (independent of C) ----
  {
    const int n3l = 1;
    float e3[8];
    ext_level<9, 0, 7, true>(e4v, l3r[n3l ^ 1], e3);
#pragma unroll
    for (int c2 = 0; c2 < 2; ++c2) {
      const int n2l = 2 * n3l + c2;
      float e2v[8];
      ext_level<5, 4, 7, true>(e3, l2r[n2l ^ 1], e2v);
#pragma unroll
      for (int c1i = 0; c1i < 2; ++c1i) {
        const int n1l = 2 * n2l + c1i;
        float sib1[3] = {0.0f, l1r[n1l ^ 1], th2r[n1l ^ 1]};
        float e1m[8];
        ext_level<3, 6, 7, true>(e2v, sib1, e1m);
        const int colL = 16 * p + 2 * n1l;
        {
          float t6 = e1m[6] + th[2 * n1l + 1];
          float t7 = e1m[7];
          float amax = fmaxf(t6, t7);
          float s = __expf(fminf(t6, t7) - amax) + 1.0f;
          mb[colL * 8] = __expf((th[2 * n1l] + (__logf(s) + amax)) - logZ);
        }
        {
          float t6 = e1m[6] + th[2 * n1l];
          float t7 = e1m[7];
          float amax = fmaxf(t6, t7);
          float s = __expf(fminf(t6, t7) - amax) + 1.0f;
          mb[(colL + 1) * 8] = __expf((th[2 * n1l + 1] + (__logf(s) + amax)) - logZ);
        }
      }
    }
  }

  // ---- remaining sampling levels ----
  uint32_t pk2 = 0;
  {  // li2: 4 tasks, J=5 static with validity guard (low overhead per draw)
#pragma unroll
    for (int i = 0; i < 4; ++i) {
      int c = c1v[i];
      float best = -3.0e38f; int bj2 = 0;
#pragma unroll
      for (int j = 0; j < 5; ++j) {
        float g = gumbel_draw(keys.v[4], keys.v[5],
                              4u * t9 + (uint32_t)(i * 9 + j));
        int idx = c - j;
        int cl = min(max(idx, 1), 4);
        float b = L(64 + (2 * i + 1) * 4 + cl - 1);
        float bf = (idx == 0) ? 0.0f : b;
        float a = (j == 0) ? 0.0f : L(64 + (2 * i) * 4 + j - 1);
        float v = (a + bf) + g;
        if (idx >= 0 && idx <= 4 && v > best) { best = v; bj2 = j; }
      }
      pk2 |= ((uint32_t)bj2 << (8 * i)) | ((uint32_t)(c - bj2) << (8 * i + 4));
    }
  }
  uint64_t pk64 = 0;
  {  // li3: 8 tasks, J=3 static with validity guard; full unroll (R17)
    const uint32_t sk0 = keys.v[6], sk1 = keys.v[7];
    const uint32_t fb0 = 8u * t9;
#pragma unroll
    for (int i = 0; i < 8; ++i) {
      int c = (int)((pk2 >> (4 * i)) & 15u);
      float aL1 = L(32 + 2 * i), aL2 = L(48 + 2 * i);
      float bR1 = L(32 + 2 * i + 1), bR2 = L(48 + 2 * i + 1);
      uint32_t fb = fb0 + (uint32_t)(i * 9);
      float best = -3.0e38f; int bj3 = 0;
#pragma unroll
      for (int j = 0; j < 3; ++j) {
        float g = gumbel_draw(sk0, sk1, fb + (uint32_t)j);
        int idx = c - j;
        float bf = (idx == 1) ? bR1 : ((idx == 2) ? bR2 : 0.0f);
        float af = (j == 0) ? 0.0f : ((j == 1) ? aL1 : aL2);
        float v = (af + bf) + g;
        if (idx >= 0 && idx <= 2 && v > best) { best = v; bj3 = j; }
      }
      pk64 |= ((uint64_t)(uint32_t)bj3 << (8 * i)) |
              ((uint64_t)(uint32_t)(c - bj3) << (8 * i + 4));
    }
  }
  {  // li4: draws ONLY for c==1 leaf pairs (c=0 -> bj=0, c=2 -> bj=1).
     // Static 8 slots (m4 <= 8 since sum of leaf-pair counts = 8);
     // live=(tt<m4) guard; dead slots decode nibble 0 -> read L(0)/L(1)
     // (in-bounds), waste a draw, skip the store. Wave cost unchanged.
    const uint32_t sk0 = keys.v[8], sk1 = keys.v[9];
    const uint32_t fb0 = 16u * t9;
    float* bs = out + p * (B * 32) + node * 256 + e;
    uint32_t lst = 0; int m4 = 0;
#pragma unroll
    for (int i = 0; i < 16; ++i) {
      int c = (int)((uint32_t)(pk64 >> (4 * i)) & 15u);
      if (c == 1) {
        lst |= ((uint32_t)i) << (4 * m4);
        ++m4;
      } else {
        int bj = c >> 1;                        // 0->0, 2->1
        bs[16 * i] = (float)bj;
        bs[16 * i + 8] = (float)(c - bj);
      }
    }
#pragma unroll
    for (int tt = 0; tt < 8; ++tt) {
      const bool live = (tt < m4);
      int i = (int)((lst >> (4 * tt)) & 15u);
      float thL = L(2 * i);
      float thR = L(2 * i + 1);
      uint32_t fb = fb0 + (uint32_t)(i * 9);
      float g0 = gumbel_draw(sk0, sk1, fb);       // j=0: 0 + thR
      float g1 = gumbel_draw(sk0, sk1, fb + 1u);  // j=1: thL + 0
      int bj = ((thL + g1) > (thR + g0)) ? 1 : 0; // first-max: strict >
      if (live) {
        bs[16 * i] = (float)bj;
        bs[16 * i + 8] = (float)(1 - bj);
      }
    }
  }
#undef L
}

extern "C" void kernel_launch(void* const* d_in, const int* in_sizes, int n_in,
                              void* d_out, int out_size, void* d_ws, size_t ws_size,
                              hipStream_t stream) {
  const float* scores = (const float*)d_in[0];
  float* out = (float*)d_out;
  const int nnodes = in_sizes[0] / (32 * 8);   // 8192
  const int B = nnodes * 8;                    // 65536 rows

  // key = jax.random.key(42); per level: key, sub = split(key)
  // (partitionable threefry: new = tf(key,(0,0)), sub = tf(key,(0,1)))
  TFKeys K;
  uint32_t k0 = 0u, k1 = 42u;
  for (int t = 0; t < 5; ++t) {
    uint32_t n0, n1, s0, s1;
    tf2x32(k0, k1, 0u, 0u, n0, n1);
    tf2x32(k0, k1, 0u, 1u, s0, s1);
    K.v[2 * t] = s0; K.v[2 * t + 1] = s1;
    k0 = n0; k1 = n1;
  }

  dim3 grid((unsigned)(B / 32)), block(64);
  hipLaunchKernelGGL(simple_sampler_kernel, grid, block, 0, stream,
                     scores, out, nnodes, K);
}